// Round 2
// baseline (276.463 us; speedup 1.0000x reference)
//
#include <hip/hip_runtime.h>
#include <stdint.h>

// Problem constants
#define NBATCH 2
#define NSEQ   4096
#define DIMF   512
#define HEADS  8
#define DHEAD  64
#define MTOK   (NBATCH*NSEQ)      // 8192 tokens
#define NBH    (NBATCH*HEADS)     // 16 (b,h) pairs

typedef __bf16 bf16x8 __attribute__((ext_vector_type(8)));
typedef float  f32x4  __attribute__((ext_vector_type(4)));
typedef short  short8v __attribute__((ext_vector_type(8)));

__device__ __forceinline__ unsigned short f2bf(float f) {
  unsigned x = __builtin_bit_cast(unsigned, f);
  x += 0x7fffu + ((x >> 16) & 1u);          // round-to-nearest-even
  return (unsigned short)(x >> 16);
}

// async global->LDS, 16B per lane. LDS dest is wave-uniform base (+lane*16 implicit).
__device__ __forceinline__ void gld16(void* lds, const void* g) {
  __builtin_amdgcn_global_load_lds(
      (const __attribute__((address_space(1))) unsigned*)g,
      (__attribute__((address_space(3))) unsigned*)lds, 16, 0, 0);
}

#if __has_builtin(__builtin_amdgcn_exp2f)
#define EXP2F __builtin_amdgcn_exp2f
#else
#define EXP2F exp2f
#endif

// ---------------------------------------------------------------- LayerNorm
__global__ __launch_bounds__(256) void ln_kernel(
    const float* __restrict__ x, const float* __restrict__ gamma,
    const float* __restrict__ beta, unsigned* __restrict__ xnb) {
  const int row = blockIdx.x;
  const int t = threadIdx.x;
  const float2 v = *(const float2*)(x + (size_t)row * DIMF + t * 2);
  float s1 = v.x + v.y;
  float s2 = v.x * v.x + v.y * v.y;
#pragma unroll
  for (int m = 1; m < 64; m <<= 1) { s1 += __shfl_xor(s1, m); s2 += __shfl_xor(s2, m); }
  __shared__ float ls1[4], ls2[4];
  const int w = t >> 6;
  if ((t & 63) == 0) { ls1[w] = s1; ls2[w] = s2; }
  __syncthreads();
  s1 = ls1[0] + ls1[1] + ls1[2] + ls1[3];
  s2 = ls2[0] + ls2[1] + ls2[2] + ls2[3];
  const float mu  = s1 * (1.0f / 512.0f);
  const float var = s2 * (1.0f / 512.0f) - mu * mu;
  const float rs  = 1.0f / sqrtf(var + 1e-5f);
  const float2 g2 = *(const float2*)(gamma + t * 2);
  const float2 b2 = *(const float2*)(beta + t * 2);
  const float a0 = (v.x - mu) * rs * g2.x + b2.x;
  const float a1 = (v.y - mu) * rs * g2.y + b2.y;
  xnb[(size_t)row * 256 + t] = (unsigned)f2bf(a0) | ((unsigned)f2bf(a1) << 16);
}

// ------------------------------------------- weight cast + transpose (once/call)
__global__ __launch_bounds__(256) void wprep_kernel(
    const float* __restrict__ wqkv, const float* __restrict__ wout,
    unsigned short* __restrict__ wqkvT, unsigned short* __restrict__ woT) {
  const int tid = blockIdx.x * 256 + threadIdx.x;
  if (tid < 512 * 1536) {
    const int c = tid % 1536, k = tid / 1536;       // coalesced read
    wqkvT[c * 512 + k] = f2bf(wqkv[(size_t)k * 1536 + c]);
  } else {
    const int i = tid - 512 * 1536;
    const int c = i % 512, k = i / 512;
    woT[c * 512 + k] = f2bf(wout[(size_t)k * 512 + c]);
  }
}

// ---------------------------------------------------------------- GEMM
// C[M][Ncols] = A[M][512] * Bt[Ncols][512]^T, bf16 in, fp32 acc.
// MODE 0: scatter epilogue -> Qb/Kb (bh,n,dh) and Vtb (bh,dh,n), bf16
// MODE 1: fp32 epilogue -> Cout + bias
template <int MODE>
__global__ __launch_bounds__(256, 2) void gemm_kernel(
    const unsigned short* __restrict__ A, const unsigned short* __restrict__ Bt,
    unsigned short* __restrict__ Qb, unsigned short* __restrict__ Kb,
    unsigned short* __restrict__ Vtb,
    const float* __restrict__ bias, float* __restrict__ Cout, int Ncols) {
  __shared__ short Ab[2][128 * 32];
  __shared__ short Bb[2][128 * 32];
  const int tid = threadIdx.x;
  const int w = tid >> 6, l = tid & 63;
  const int g = l >> 4, c = l & 15;
  const int nbn = Ncols >> 7;
  const int mb = blockIdx.x / nbn, nb = blockIdx.x % nbn;
  const int m0 = mb * 128, n0 = nb * 128;
  const int wr = w >> 1, wc = w & 1;

  f32x4 acc[4][4] = {};

  auto STAGE = [&](int buf, int kt) {
    const int k0 = kt * 32;
#pragma unroll
    for (int j = 0; j < 2; ++j) {
      const int row = w * 32 + j * 16 + (l >> 2);
      const int gk = (l & 3) ^ ((row >> 1) & 3);   // pre-swizzled source
      gld16(&Ab[buf][(w * 32 + j * 16) * 32], A + (size_t)(m0 + row) * 512 + k0 + gk * 8);
      gld16(&Bb[buf][(w * 32 + j * 16) * 32], Bt + (size_t)(n0 + row) * 512 + k0 + gk * 8);
    }
  };

  STAGE(0, 0);
  __syncthreads();

  for (int kt = 0; kt < 16; ++kt) {
    const int buf = kt & 1;
    if (kt + 1 < 16) STAGE(buf ^ 1, kt + 1);
    bf16x8 af[4], bfr[4];
#pragma unroll
    for (int rt = 0; rt < 4; ++rt) {
      const int row = wr * 64 + rt * 16 + c;
      const int slot = g ^ ((row >> 1) & 3);
      af[rt] = __builtin_bit_cast(bf16x8, *(const short8v*)&Ab[buf][row * 32 + slot * 8]);
    }
#pragma unroll
    for (int nt = 0; nt < 4; ++nt) {
      const int row = wc * 64 + nt * 16 + c;
      const int slot = g ^ ((row >> 1) & 3);
      bfr[nt] = __builtin_bit_cast(bf16x8, *(const short8v*)&Bb[buf][row * 32 + slot * 8]);
    }
#pragma unroll
    for (int rt = 0; rt < 4; ++rt)
#pragma unroll
      for (int nt = 0; nt < 4; ++nt)
        acc[rt][nt] = __builtin_amdgcn_mfma_f32_16x16x32_bf16(af[rt], bfr[nt], acc[rt][nt], 0, 0, 0);
    __syncthreads();
  }

#pragma unroll
  for (int rt = 0; rt < 4; ++rt)
#pragma unroll
    for (int nt = 0; nt < 4; ++nt) {
      const int col = n0 + wc * 64 + nt * 16 + c;
#pragma unroll
      for (int r = 0; r < 4; ++r) {
        const int m = m0 + wr * 64 + rt * 16 + g * 4 + r;
        const float v = acc[rt][nt][r];
        if (MODE == 0) {
          const int sec = col >> 9, hh = (col >> 6) & 7, dh = col & 63;
          const int bh = (m >> 12) * 8 + hh, n = m & 4095;
          const unsigned short bv = f2bf(v);
          if (sec == 0)      Qb[(size_t)(bh * 4096 + n) * 64 + dh] = bv;
          else if (sec == 1) Kb[(size_t)(bh * 4096 + n) * 64 + dh] = bv;
          else               Vtb[(size_t)(bh * 64 + dh) * 4096 + n] = bv;
        } else {
          Cout[(size_t)m * 512 + col] = v + bias[col];
        }
      }
    }
}

// ---------------------------------------------------------------- attention
// grid 256 = qb*16 + bh (bid%8 fixed per bh -> same-bh blocks co-XCD for L2 reuse).
// 4 waves x 64 q-rows, KV tile 64, fixed-bias softmax exp(s/8 - 10).
// Swapped QK^T: S^T = mfma(K, Q) -> lane holds q=c, 4 consecutive keys ->
// packed b64 writes into per-wave P LDS in [q][key] layout (XOR-swizzled),
// PV A-fragment is then a contiguous swizzled ds_read_b128. No tr_b16.
__global__ __launch_bounds__(256) void attn_kernel(
    const unsigned short* __restrict__ Qb, const unsigned short* __restrict__ Kb,
    const unsigned short* __restrict__ Vtb, unsigned short* __restrict__ attnb) {
  __shared__ short Kbuf[2][64 * 64];
  __shared__ short Vbuf[2][64 * 64];
  __shared__ short PT[4][64 * 64];              // per-wave P: [q][key], swizzled
  __shared__ float lsums[4][64];                // per-wave 1/rowsum
  const int tid = threadIdx.x;
  const int w = tid >> 6, l = tid & 63;
  const int g = l >> 4, c = l & 15, c7 = l & 7;
  const int bh = blockIdx.x & 15, qb = blockIdx.x >> 4;
  const int q0 = qb * 256 + w * 64;
  const unsigned short* Qp = Qb + (size_t)(bh * 4096 + q0) * 64;
  const unsigned short* Kp = Kb + (size_t)bh * 4096 * 64;
  const unsigned short* Vp = Vtb + (size_t)bh * 64 * 4096;

  // Q as B-fragments: lane holds Q[q = qt*16+c][d = kk*32 + g*8 + j]
  bf16x8 qf[4][2];
#pragma unroll
  for (int qt = 0; qt < 4; ++qt)
#pragma unroll
    for (int kk = 0; kk < 2; ++kk)
      qf[qt][kk] = __builtin_bit_cast(bf16x8,
          *(const short8v*)(Qp + (size_t)(qt * 16 + c) * 64 + kk * 32 + g * 8));

  f32x4 O[4][4] = {};
  float lsum[4] = {0.f, 0.f, 0.f, 0.f};
  char* Pw = (char*)&PT[w][0];

  auto STAGEKV = [&](int buf, int t) {
    const int kv0 = t * 64;
#pragma unroll
    for (int j = 0; j < 2; ++j) {
      const int row = w * 16 + j * 8 + (l >> 3);
      const int gk = (l & 7) ^ (row & 7);        // pre-swizzled source
      gld16(&Kbuf[buf][(w * 16 + j * 8) * 64], Kp + (size_t)(kv0 + row) * 64 + gk * 8);
      gld16(&Vbuf[buf][(w * 16 + j * 8) * 64], Vp + (size_t)row * 4096 + kv0 + gk * 8);
    }
  };

  STAGEKV(0, 0);
  __syncthreads();

  const float C1 = 0.125f * 1.4426950408889634f;   // scale * log2(e)
  const float C2 = 10.0f * 1.4426950408889634f;    // fixed softmax bias

  for (int t = 0; t < 64; ++t) {
    const int buf = t & 1;
    if (t + 1 < 64) STAGEKV(buf ^ 1, t + 1);

    // ---- swapped QK^T: S^T[key][q] = K · Q^T, then exp + packed P write
#pragma unroll
    for (int kt = 0; kt < 4; ++kt) {
      const int krow = kt * 16 + c;
      bf16x8 kf0 = __builtin_bit_cast(bf16x8,
          *(const short8v*)&Kbuf[buf][krow * 64 + ((0 * 4 + g) ^ c7) * 8]);
      bf16x8 kf1 = __builtin_bit_cast(bf16x8,
          *(const short8v*)&Kbuf[buf][krow * 64 + ((1 * 4 + g) ^ c7) * 8]);
#pragma unroll
      for (int qt = 0; qt < 4; ++qt) {
        f32x4 S = {};
        S = __builtin_amdgcn_mfma_f32_16x16x32_bf16(kf0, qf[qt][0], S, 0, 0, 0);
        S = __builtin_amdgcn_mfma_f32_16x16x32_bf16(kf1, qf[qt][1], S, 0, 0, 0);
        const float p0 = EXP2F(S[0] * C1 - C2);
        const float p1 = EXP2F(S[1] * C1 - C2);
        const float p2 = EXP2F(S[2] * C1 - C2);
        const float p3 = EXP2F(S[3] * C1 - C2);
        lsum[qt] += (p0 + p1) + (p2 + p3);
        const unsigned u0 = (unsigned)f2bf(p0) | ((unsigned)f2bf(p1) << 16);
        const unsigned u1 = (unsigned)f2bf(p2) | ((unsigned)f2bf(p3) << 16);
        // P[q = qt*16+c][keys kt*16+g*4 .. +3], byte swizzle ^ (c7*16) (bits 4-6)
        *(uint2*)(Pw + (qt * 16 + c) * 128 + ((kt * 32 + g * 8) ^ (c7 * 16))) =
            make_uint2(u0, u1);
      }
    }

    // ---- PV: O[q][d] += P · V, A = P from LDS (contig b128), B = V^T frags
    bf16x8 vf[4][2];
#pragma unroll
    for (int nt = 0; nt < 4; ++nt) {
      const int vrow = nt * 16 + c;
#pragma unroll
      for (int kk = 0; kk < 2; ++kk)
        vf[nt][kk] = __builtin_bit_cast(bf16x8,
            *(const short8v*)&Vbuf[buf][vrow * 64 + (((kk * 4 + g) ^ c7) * 8)]);
    }
#pragma unroll
    for (int rt = 0; rt < 4; ++rt)
#pragma unroll
      for (int kk = 0; kk < 2; ++kk) {
        bf16x8 pa = __builtin_bit_cast(bf16x8,
            *(const short8v*)(Pw + (rt * 16 + c) * 128 + ((kk * 64 + g * 16) ^ (c7 * 16))));
#pragma unroll
        for (int nt = 0; nt < 4; ++nt)
          O[rt][nt] = __builtin_amdgcn_mfma_f32_16x16x32_bf16(pa, vf[nt][kk], O[rt][nt], 0, 0, 0);
      }
    __syncthreads();
  }

  // ---- denominators: lane owns q = qt*16+c; combine the 4 g-groups
  float lv[4][4];
#pragma unroll
  for (int qt = 0; qt < 4; ++qt) {
    float s = lsum[qt];
    s += __shfl_xor(s, 16);
    s += __shfl_xor(s, 32);
    if (l < 16) lsums[w][qt * 16 + l] = 1.0f / s;
  }
#pragma unroll
  for (int rt = 0; rt < 4; ++rt) {
    const f32x4 t4 = *(const f32x4*)&lsums[w][rt * 16 + g * 4];  // broadcast read
#pragma unroll
    for (int r = 0; r < 4; ++r) lv[rt][r] = t4[r];
  }

  const int tok0 = (bh >> 3) * 4096 + q0;
  const int col0 = (bh & 7) * 64;
#pragma unroll
  for (int rt = 0; rt < 4; ++rt)
#pragma unroll
    for (int nt = 0; nt < 4; ++nt)
#pragma unroll
      for (int r = 0; r < 4; ++r) {
        const int tok = tok0 + rt * 16 + g * 4 + r;
        attnb[(size_t)tok * 512 + col0 + nt * 16 + c] = f2bf(O[rt][nt][r] * lv[rt][r]);
      }
}

// ---------------------------------------------------------------- launch
extern "C" void kernel_launch(void* const* d_in, const int* in_sizes, int n_in,
                              void* d_out, int out_size, void* d_ws, size_t ws_size,
                              hipStream_t stream) {
  (void)in_sizes; (void)n_in; (void)out_size; (void)ws_size;
  const float* x     = (const float*)d_in[0];
  const float* gamma = (const float*)d_in[1];
  const float* beta  = (const float*)d_in[2];
  const float* wqkv  = (const float*)d_in[3];
  const float* wout  = (const float*)d_in[4];
  const float* bout  = (const float*)d_in[5];
  float* out = (float*)d_out;

  char* ws = (char*)d_ws;
  size_t off = 0;
  auto alloc = [&](size_t bytes) {
    void* p = ws + off;
    off += (bytes + 255) & ~(size_t)255;
    return p;
  };
  unsigned*       xnb   = (unsigned*)alloc((size_t)MTOK * DIMF * 2);
  unsigned short* wqkvT = (unsigned short*)alloc((size_t)1536 * 512 * 2);
  unsigned short* woT   = (unsigned short*)alloc((size_t)512 * 512 * 2);
  unsigned short* Qbuf  = (unsigned short*)alloc((size_t)NBH * NSEQ * DHEAD * 2);
  unsigned short* Kb    = (unsigned short*)alloc((size_t)NBH * NSEQ * DHEAD * 2);
  unsigned short* Vtb   = (unsigned short*)alloc((size_t)NBH * NSEQ * DHEAD * 2);
  unsigned short* attnb = (unsigned short*)alloc((size_t)MTOK * DIMF * 2);

  ln_kernel<<<dim3(MTOK), dim3(256), 0, stream>>>(x, gamma, beta, xnb);
  wprep_kernel<<<dim3(4096), dim3(256), 0, stream>>>(wqkv, wout, wqkvT, woT);
  gemm_kernel<0><<<dim3(64 * 12), dim3(256), 0, stream>>>(
      (const unsigned short*)xnb, wqkvT, Qbuf, Kb, Vtb, nullptr, nullptr, 1536);
  attn_kernel<<<dim3(256), dim3(256), 0, stream>>>(Qbuf, Kb, Vtb, attnb);
  gemm_kernel<1><<<dim3(64 * 4), dim3(256), 0, stream>>>(
      attnb, woT, nullptr, nullptr, nullptr, bout, out, 512);
}

// Round 3
// 243.250 us; speedup vs baseline: 1.1365x; 1.1365x over previous
//
#include <hip/hip_runtime.h>
#include <stdint.h>

// Problem constants
#define NBATCH 2
#define NSEQ   4096
#define DIMF   512
#define HEADS  8
#define DHEAD  64
#define MTOK   (NBATCH*NSEQ)      // 8192 tokens
#define NBH    (NBATCH*HEADS)     // 16 (b,h) pairs

typedef __bf16 bf16x8 __attribute__((ext_vector_type(8)));
typedef float  f32x4  __attribute__((ext_vector_type(4)));
typedef short  short8v __attribute__((ext_vector_type(8)));

__device__ __forceinline__ unsigned short f2bf(float f) {
  unsigned x = __builtin_bit_cast(unsigned, f);
  x += 0x7fffu + ((x >> 16) & 1u);          // round-to-nearest-even
  return (unsigned short)(x >> 16);
}

// async global->LDS, 16B per lane. LDS dest is wave-uniform base (+lane*16 implicit).
__device__ __forceinline__ void gld16(void* lds, const void* g) {
  __builtin_amdgcn_global_load_lds(
      (const __attribute__((address_space(1))) unsigned*)g,
      (__attribute__((address_space(3))) unsigned*)lds, 16, 0, 0);
}

// ---------------------------------------------------------------- LayerNorm
__global__ __launch_bounds__(256) void ln_kernel(
    const float* __restrict__ x, const float* __restrict__ gamma,
    const float* __restrict__ beta, unsigned* __restrict__ xnb) {
  const int row = blockIdx.x;
  const int t = threadIdx.x;
  const float2 v = *(const float2*)(x + (size_t)row * DIMF + t * 2);
  float s1 = v.x + v.y;
  float s2 = v.x * v.x + v.y * v.y;
#pragma unroll
  for (int m = 1; m < 64; m <<= 1) { s1 += __shfl_xor(s1, m); s2 += __shfl_xor(s2, m); }
  __shared__ float ls1[4], ls2[4];
  const int w = t >> 6;
  if ((t & 63) == 0) { ls1[w] = s1; ls2[w] = s2; }
  __syncthreads();
  s1 = ls1[0] + ls1[1] + ls1[2] + ls1[3];
  s2 = ls2[0] + ls2[1] + ls2[2] + ls2[3];
  const float mu  = s1 * (1.0f / 512.0f);
  const float var = s2 * (1.0f / 512.0f) - mu * mu;
  const float rs  = 1.0f / sqrtf(var + 1e-5f);
  const float2 g2 = *(const float2*)(gamma + t * 2);
  const float2 b2 = *(const float2*)(beta + t * 2);
  const float a0 = (v.x - mu) * rs * g2.x + b2.x;
  const float a1 = (v.y - mu) * rs * g2.y + b2.y;
  xnb[(size_t)row * 256 + t] = (unsigned)f2bf(a0) | ((unsigned)f2bf(a1) << 16);
}

// ------------------------------------------- weight cast + transpose (once/call)
__global__ __launch_bounds__(256) void wprep_kernel(
    const float* __restrict__ wqkv, const float* __restrict__ wout,
    unsigned short* __restrict__ wqkvT, unsigned short* __restrict__ woT) {
  const int tid = blockIdx.x * 256 + threadIdx.x;
  if (tid < 512 * 1536) {
    const int c = tid % 1536, k = tid / 1536;       // coalesced read
    wqkvT[c * 512 + k] = f2bf(wqkv[(size_t)k * 1536 + c]);
  } else {
    const int i = tid - 512 * 1536;
    const int c = i % 512, k = i / 512;
    woT[c * 512 + k] = f2bf(wout[(size_t)k * 512 + c]);
  }
}

// ---------------------------------------------------------------- GEMM
// C[M][Ncols] = A[M][512] * Bt[Ncols][512]^T, bf16 in, fp32 acc.
// MODE 0: scatter epilogue -> Qb (scaled by 1/8*log2e), Kb, Vb all [bh][n][64]
// MODE 1: fp32 epilogue -> Cout + bias
template <int MODE>
__global__ __launch_bounds__(256, 2) void gemm_kernel(
    const unsigned short* __restrict__ A, const unsigned short* __restrict__ Bt,
    unsigned short* __restrict__ Qb, unsigned short* __restrict__ Kb,
    unsigned short* __restrict__ Vb,
    const float* __restrict__ bias, float* __restrict__ Cout, int Ncols) {
  __shared__ short Ab[2][128 * 32];
  __shared__ short Bb[2][128 * 32];
  const int tid = threadIdx.x;
  const int w = tid >> 6, l = tid & 63;
  const int g = l >> 4, c = l & 15;
  const int nbn = Ncols >> 7;
  const int mb = blockIdx.x / nbn, nb = blockIdx.x % nbn;
  const int m0 = mb * 128, n0 = nb * 128;
  const int wr = w >> 1, wc = w & 1;

  f32x4 acc[4][4] = {};

  auto STAGE = [&](int buf, int kt) {
    const int k0 = kt * 32;
#pragma unroll
    for (int j = 0; j < 2; ++j) {
      const int row = w * 32 + j * 16 + (l >> 2);
      const int gk = (l & 3) ^ ((row >> 1) & 3);   // pre-swizzled source
      gld16(&Ab[buf][(w * 32 + j * 16) * 32], A + (size_t)(m0 + row) * 512 + k0 + gk * 8);
      gld16(&Bb[buf][(w * 32 + j * 16) * 32], Bt + (size_t)(n0 + row) * 512 + k0 + gk * 8);
    }
  };

  STAGE(0, 0);
  __syncthreads();

  for (int kt = 0; kt < 16; ++kt) {
    const int buf = kt & 1;
    if (kt + 1 < 16) STAGE(buf ^ 1, kt + 1);
    bf16x8 af[4], bfr[4];
#pragma unroll
    for (int rt = 0; rt < 4; ++rt) {
      const int row = wr * 64 + rt * 16 + c;
      const int slot = g ^ ((row >> 1) & 3);
      af[rt] = __builtin_bit_cast(bf16x8, *(const short8v*)&Ab[buf][row * 32 + slot * 8]);
    }
#pragma unroll
    for (int nt = 0; nt < 4; ++nt) {
      const int row = wc * 64 + nt * 16 + c;
      const int slot = g ^ ((row >> 1) & 3);
      bfr[nt] = __builtin_bit_cast(bf16x8, *(const short8v*)&Bb[buf][row * 32 + slot * 8]);
    }
#pragma unroll
    for (int rt = 0; rt < 4; ++rt)
#pragma unroll
      for (int nt = 0; nt < 4; ++nt)
        acc[rt][nt] = __builtin_amdgcn_mfma_f32_16x16x32_bf16(af[rt], bfr[nt], acc[rt][nt], 0, 0, 0);
    __syncthreads();
  }

#pragma unroll
  for (int rt = 0; rt < 4; ++rt)
#pragma unroll
    for (int nt = 0; nt < 4; ++nt) {
      const int col = n0 + wc * 64 + nt * 16 + c;
#pragma unroll
      for (int r = 0; r < 4; ++r) {
        const int m = m0 + wr * 64 + rt * 16 + g * 4 + r;
        const float v = acc[rt][nt][r];
        if (MODE == 0) {
          const int sec = col >> 9, hh = (col >> 6) & 7, dh = col & 63;
          const int bh = (m >> 12) * 8 + hh, n = m & 4095;
          const size_t idx = (size_t)(bh * 4096 + n) * 64 + dh;
          if (sec == 0)      Qb[idx] = f2bf(v * 0.18033688011112042f); // 1/8*log2(e)
          else if (sec == 1) Kb[idx] = f2bf(v);
          else               Vb[idx] = f2bf(v);
        } else {
          Cout[(size_t)m * 512 + col] = v + bias[col];
        }
      }
    }
}

// ------------------------------------------- V transpose: [bh][n][64] -> [bh][64][n]
__global__ __launch_bounds__(256) void vtrans_kernel(
    const unsigned short* __restrict__ Vb, unsigned short* __restrict__ Vtb) {
  __shared__ unsigned short tl[64][72];          // 72: 16B-aligned rows, bank-spread
  const int tid = threadIdx.x;
  const int bh = blockIdx.x >> 6, nt = blockIdx.x & 63;
  const int n0 = nt * 64;
  const unsigned short* src = Vb + ((size_t)bh * 4096 + n0) * 64;
#pragma unroll
  for (int h = 0; h < 2; ++h) {
    const int r = (tid >> 3) + h * 32;
    const int c0 = (tid & 7) * 8;
    *(short8v*)&tl[r][c0] = *(const short8v*)(src + r * 64 + c0);
  }
  __syncthreads();
#pragma unroll
  for (int h = 0; h < 2; ++h) {
    const int d = (tid >> 3) + h * 32;
    const int m0 = (tid & 7) * 8;
    unsigned short tmp[8];
#pragma unroll
    for (int i = 0; i < 8; ++i) tmp[i] = tl[m0 + i][d];
    *(short8v*)(Vtb + ((size_t)bh * 64 + d) * 4096 + n0 + m0) = *(const short8v*)&tmp[0];
  }
}

// ---------------------------------------------------------------- attention
// grid 512 = qb*16 + bh (same-bh blocks share an XCD -> K/V L2-resident).
// 4 waves x 32 q-rows, KV tile 64, no-max softmax exp2(S) (scale folded into Q).
// Swapped QK^T: S^T = mfma(K, Q) -> lane holds q=c, 4 consecutive keys ->
// packed b64 writes into per-wave P LDS [q][key] (XOR-swizzled),
// PV A-frag = contiguous swizzled ds_read_b128. Row-sums via mfma(P, ones).
__global__ __launch_bounds__(256, 2) void attn_kernel(
    const unsigned short* __restrict__ Qb, const unsigned short* __restrict__ Kb,
    const unsigned short* __restrict__ Vtb, unsigned short* __restrict__ attnb) {
  __shared__ short Kbuf[2][64 * 64];
  __shared__ short Vbuf[2][64 * 64];
  __shared__ short PT[4][32 * 64];              // per-wave P: [q][key], swizzled
  const int tid = threadIdx.x;
  const int w = tid >> 6, l = tid & 63;
  const int g = l >> 4, c = l & 15, c7 = l & 7;
  const int bh = blockIdx.x & 15, qb = blockIdx.x >> 4;   // qb 0..31
  const int q0 = qb * 128 + w * 32;
  const unsigned short* Qp = Qb + (size_t)(bh * 4096 + q0) * 64;
  const unsigned short* Kp = Kb + (size_t)bh * 4096 * 64;
  const unsigned short* Vp = Vtb + (size_t)bh * 64 * 4096;

  // Q as B-fragments: lane holds Q[q = qt*16+c][d = kk*32 + g*8 + j] (pre-scaled)
  bf16x8 qf[2][2];
#pragma unroll
  for (int qt = 0; qt < 2; ++qt)
#pragma unroll
    for (int kk = 0; kk < 2; ++kk)
      qf[qt][kk] = __builtin_bit_cast(bf16x8,
          *(const short8v*)(Qp + (size_t)(qt * 16 + c) * 64 + kk * 32 + g * 8));

  // ones B-fragment for rowsum-by-MFMA
  short8v ones_s;
#pragma unroll
  for (int i = 0; i < 8; ++i) ones_s[i] = (short)0x3f80;  // bf16 1.0
  const bf16x8 ones = __builtin_bit_cast(bf16x8, ones_s);

  f32x4 O[2][4] = {};
  f32x4 osum[2] = {};
  char* Pw = (char*)&PT[w][0];

  auto STAGEKV = [&](int buf, int t) {
    const int kv0 = t * 64;
#pragma unroll
    for (int j = 0; j < 2; ++j) {
      const int row = w * 16 + j * 8 + (l >> 3);
      const int gk = (l & 7) ^ (row & 7);        // pre-swizzled source
      gld16(&Kbuf[buf][(w * 16 + j * 8) * 64], Kp + (size_t)(kv0 + row) * 64 + gk * 8);
      gld16(&Vbuf[buf][(w * 16 + j * 8) * 64], Vp + (size_t)row * 4096 + kv0 + gk * 8);
    }
  };

  STAGEKV(0, 0);
  __syncthreads();

  for (int t = 0; t < 64; ++t) {
    const int buf = t & 1;
    if (t + 1 < 64) STAGEKV(buf ^ 1, t + 1);

    // ---- swapped QK^T: S^T[key][q] = K · Q^T, exp2, packed P write
#pragma unroll
    for (int kt = 0; kt < 4; ++kt) {
      const int krow = kt * 16 + c;
      bf16x8 kf0 = __builtin_bit_cast(bf16x8,
          *(const short8v*)&Kbuf[buf][krow * 64 + ((0 * 4 + g) ^ c7) * 8]);
      bf16x8 kf1 = __builtin_bit_cast(bf16x8,
          *(const short8v*)&Kbuf[buf][krow * 64 + ((1 * 4 + g) ^ c7) * 8]);
#pragma unroll
      for (int qt = 0; qt < 2; ++qt) {
        f32x4 S = {};
        S = __builtin_amdgcn_mfma_f32_16x16x32_bf16(kf0, qf[qt][0], S, 0, 0, 0);
        S = __builtin_amdgcn_mfma_f32_16x16x32_bf16(kf1, qf[qt][1], S, 0, 0, 0);
        const float p0 = exp2f(S[0]);
        const float p1 = exp2f(S[1]);
        const float p2 = exp2f(S[2]);
        const float p3 = exp2f(S[3]);
        unsigned u0, u1;
        asm("v_cvt_pk_bf16_f32 %0, %1, %2" : "=v"(u0) : "v"(p0), "v"(p1));
        asm("v_cvt_pk_bf16_f32 %0, %1, %2" : "=v"(u1) : "v"(p2), "v"(p3));
        // P[q = qt*16+c][keys kt*16+g*4 .. +3], byte swizzle ^ (c7*16) (bits 4-6)
        *(uint2*)(Pw + (qt * 16 + c) * 128 + ((kt * 32 + g * 8) ^ (c7 * 16))) =
            make_uint2(u0, u1);
      }
    }

    // ---- PV: O[q][d] += P · V ; rowsums via mfma(P, ones)
    bf16x8 vf[4][2];
#pragma unroll
    for (int nt = 0; nt < 4; ++nt) {
      const int vrow = nt * 16 + c;
#pragma unroll
      for (int kk = 0; kk < 2; ++kk)
        vf[nt][kk] = __builtin_bit_cast(bf16x8,
            *(const short8v*)&Vbuf[buf][vrow * 64 + (((kk * 4 + g) ^ c7) * 8)]);
    }
#pragma unroll
    for (int rt = 0; rt < 2; ++rt)
#pragma unroll
      for (int kk = 0; kk < 2; ++kk) {
        bf16x8 pa = __builtin_bit_cast(bf16x8,
            *(const short8v*)(Pw + (rt * 16 + c) * 128 + ((kk * 64 + g * 16) ^ (c7 * 16))));
        osum[rt] = __builtin_amdgcn_mfma_f32_16x16x32_bf16(pa, ones, osum[rt], 0, 0, 0);
#pragma unroll
        for (int nt = 0; nt < 4; ++nt)
          O[rt][nt] = __builtin_amdgcn_mfma_f32_16x16x32_bf16(pa, vf[nt][kk], O[rt][nt], 0, 0, 0);
      }
    __syncthreads();
  }

  // ---- normalize + store. osum lane(g,c) reg r = rowsum(q = rt*16+g*4+r).
  float linv[2][4];
#pragma unroll
  for (int rt = 0; rt < 2; ++rt)
#pragma unroll
    for (int r = 0; r < 4; ++r) linv[rt][r] = 1.0f / osum[rt][r];

  const int tok0 = (bh >> 3) * 4096 + q0;
  const int col0 = (bh & 7) * 64;
#pragma unroll
  for (int rt = 0; rt < 2; ++rt)
#pragma unroll
    for (int nt = 0; nt < 4; ++nt)
#pragma unroll
      for (int r = 0; r < 4; ++r) {
        const int tok = tok0 + rt * 16 + g * 4 + r;
        attnb[(size_t)tok * 512 + col0 + nt * 16 + c] = f2bf(O[rt][nt][r] * linv[rt][r]);
      }
}

// ---------------------------------------------------------------- launch
extern "C" void kernel_launch(void* const* d_in, const int* in_sizes, int n_in,
                              void* d_out, int out_size, void* d_ws, size_t ws_size,
                              hipStream_t stream) {
  (void)in_sizes; (void)n_in; (void)out_size; (void)ws_size;
  const float* x     = (const float*)d_in[0];
  const float* gamma = (const float*)d_in[1];
  const float* beta  = (const float*)d_in[2];
  const float* wqkv  = (const float*)d_in[3];
  const float* wout  = (const float*)d_in[4];
  const float* bout  = (const float*)d_in[5];
  float* out = (float*)d_out;

  char* ws = (char*)d_ws;
  size_t off = 0;
  auto alloc = [&](size_t bytes) {
    void* p = ws + off;
    off += (bytes + 255) & ~(size_t)255;
    return p;
  };
  unsigned*       xnb   = (unsigned*)alloc((size_t)MTOK * DIMF * 2);
  unsigned short* wqkvT = (unsigned short*)alloc((size_t)1536 * 512 * 2);
  unsigned short* woT   = (unsigned short*)alloc((size_t)512 * 512 * 2);
  unsigned short* Qbuf  = (unsigned short*)alloc((size_t)NBH * NSEQ * DHEAD * 2);
  unsigned short* Kb    = (unsigned short*)alloc((size_t)NBH * NSEQ * DHEAD * 2);
  unsigned short* Vtb   = (unsigned short*)alloc((size_t)NBH * NSEQ * DHEAD * 2);
  unsigned short* attnb = (unsigned short*)alloc((size_t)MTOK * DIMF * 2);
  unsigned short* Vb    = attnb;   // alias: Vb consumed by vtrans before attn writes attnb

  ln_kernel<<<dim3(MTOK), dim3(256), 0, stream>>>(x, gamma, beta, xnb);
  wprep_kernel<<<dim3(4096), dim3(256), 0, stream>>>(wqkv, wout, wqkvT, woT);
  gemm_kernel<0><<<dim3(64 * 12), dim3(256), 0, stream>>>(
      (const unsigned short*)xnb, wqkvT, Qbuf, Kb, Vb, nullptr, nullptr, 1536);
  vtrans_kernel<<<dim3(NBH * 64), dim3(256), 0, stream>>>(Vb, Vtb);
  attn_kernel<<<dim3(512), dim3(256), 0, stream>>>(Qbuf, Kb, Vtb, attnb);
  gemm_kernel<1><<<dim3(64 * 4), dim3(256), 0, stream>>>(
      attnb, woT, nullptr, nullptr, nullptr, bout, out, 512);
}

// Round 4
// 230.472 us; speedup vs baseline: 1.1996x; 1.0554x over previous
//
#include <hip/hip_runtime.h>
#include <stdint.h>

// Problem constants
#define NBATCH 2
#define NSEQ   4096
#define DIMF   512
#define HEADS  8
#define DHEAD  64
#define MTOK   (NBATCH*NSEQ)      // 8192 tokens
#define NBH    (NBATCH*HEADS)     // 16 (b,h) pairs

typedef __bf16 bf16x8 __attribute__((ext_vector_type(8)));
typedef float  f32x4  __attribute__((ext_vector_type(4)));
typedef short  short8v __attribute__((ext_vector_type(8)));
typedef unsigned uint4v __attribute__((ext_vector_type(4)));

__device__ __forceinline__ unsigned short f2bf(float f) {
  unsigned x = __builtin_bit_cast(unsigned, f);
  x += 0x7fffu + ((x >> 16) & 1u);          // round-to-nearest-even
  return (unsigned short)(x >> 16);
}

// async global->LDS, 16B per lane. LDS dest is wave-uniform base (+lane*16 implicit).
__device__ __forceinline__ void gld16(void* lds, const void* g) {
  __builtin_amdgcn_global_load_lds(
      (const __attribute__((address_space(1))) unsigned*)g,
      (__attribute__((address_space(3))) unsigned*)lds, 16, 0, 0);
}

// ---------------------------------------------------------------- LayerNorm
__global__ __launch_bounds__(256) void ln_kernel(
    const float* __restrict__ x, const float* __restrict__ gamma,
    const float* __restrict__ beta, unsigned* __restrict__ xnb) {
  const int row = blockIdx.x;
  const int t = threadIdx.x;
  const float2 v = *(const float2*)(x + (size_t)row * DIMF + t * 2);
  float s1 = v.x + v.y;
  float s2 = v.x * v.x + v.y * v.y;
#pragma unroll
  for (int m = 1; m < 64; m <<= 1) { s1 += __shfl_xor(s1, m); s2 += __shfl_xor(s2, m); }
  __shared__ float ls1[4], ls2[4];
  const int w = t >> 6;
  if ((t & 63) == 0) { ls1[w] = s1; ls2[w] = s2; }
  __syncthreads();
  s1 = ls1[0] + ls1[1] + ls1[2] + ls1[3];
  s2 = ls2[0] + ls2[1] + ls2[2] + ls2[3];
  const float mu  = s1 * (1.0f / 512.0f);
  const float var = s2 * (1.0f / 512.0f) - mu * mu;
  const float rs  = 1.0f / sqrtf(var + 1e-5f);
  const float2 g2 = *(const float2*)(gamma + t * 2);
  const float2 b2 = *(const float2*)(beta + t * 2);
  const float a0 = (v.x - mu) * rs * g2.x + b2.x;
  const float a1 = (v.y - mu) * rs * g2.y + b2.y;
  xnb[(size_t)row * 256 + t] = (unsigned)f2bf(a0) | ((unsigned)f2bf(a1) << 16);
}

// ------------------------------------------- weight cast + transpose (once/call)
__global__ __launch_bounds__(256) void wprep_kernel(
    const float* __restrict__ wqkv, const float* __restrict__ wout,
    unsigned short* __restrict__ wqkvT, unsigned short* __restrict__ woT) {
  const int tid = blockIdx.x * 256 + threadIdx.x;
  if (tid < 512 * 1536) {
    const int c = tid % 1536, k = tid / 1536;       // coalesced read
    wqkvT[c * 512 + k] = f2bf(wqkv[(size_t)k * 1536 + c]);
  } else {
    const int i = tid - 512 * 1536;
    const int c = i % 512, k = i / 512;
    woT[c * 512 + k] = f2bf(wout[(size_t)k * 512 + c]);
  }
}

// ---------------------------------------------------------------- GEMM
// C[M][Ncols] = A[M][512] * Bt[Ncols][512]^T, bf16 in, fp32 acc.
// MODE 0: scatter epilogue -> Qb (scaled by 1/8*log2e), Kb, Vb all [bh][n][64]
// MODE 1: fp32 epilogue -> Cout + bias
template <int MODE>
__global__ __launch_bounds__(256, 2) void gemm_kernel(
    const unsigned short* __restrict__ A, const unsigned short* __restrict__ Bt,
    unsigned short* __restrict__ Qb, unsigned short* __restrict__ Kb,
    unsigned short* __restrict__ Vb,
    const float* __restrict__ bias, float* __restrict__ Cout, int Ncols) {
  __shared__ short Ab[2][128 * 32];
  __shared__ short Bb[2][128 * 32];
  const int tid = threadIdx.x;
  const int w = tid >> 6, l = tid & 63;
  const int g = l >> 4, c = l & 15;
  const int nbn = Ncols >> 7;
  const int mb = blockIdx.x / nbn, nb = blockIdx.x % nbn;
  const int m0 = mb * 128, n0 = nb * 128;
  const int wr = w >> 1, wc = w & 1;

  f32x4 acc[4][4] = {};

  auto STAGE = [&](int buf, int kt) {
    const int k0 = kt * 32;
#pragma unroll
    for (int j = 0; j < 2; ++j) {
      const int row = w * 32 + j * 16 + (l >> 2);
      const int gk = (l & 3) ^ ((row >> 1) & 3);   // pre-swizzled source
      gld16(&Ab[buf][(w * 32 + j * 16) * 32], A + (size_t)(m0 + row) * 512 + k0 + gk * 8);
      gld16(&Bb[buf][(w * 32 + j * 16) * 32], Bt + (size_t)(n0 + row) * 512 + k0 + gk * 8);
    }
  };

  STAGE(0, 0);
  __syncthreads();

  for (int kt = 0; kt < 16; ++kt) {
    const int buf = kt & 1;
    if (kt + 1 < 16) STAGE(buf ^ 1, kt + 1);
    bf16x8 af[4], bfr[4];
#pragma unroll
    for (int rt = 0; rt < 4; ++rt) {
      const int row = wr * 64 + rt * 16 + c;
      const int slot = g ^ ((row >> 1) & 3);
      af[rt] = __builtin_bit_cast(bf16x8, *(const short8v*)&Ab[buf][row * 32 + slot * 8]);
    }
#pragma unroll
    for (int nt = 0; nt < 4; ++nt) {
      const int row = wc * 64 + nt * 16 + c;
      const int slot = g ^ ((row >> 1) & 3);
      bfr[nt] = __builtin_bit_cast(bf16x8, *(const short8v*)&Bb[buf][row * 32 + slot * 8]);
    }
#pragma unroll
    for (int rt = 0; rt < 4; ++rt)
#pragma unroll
      for (int nt = 0; nt < 4; ++nt)
        acc[rt][nt] = __builtin_amdgcn_mfma_f32_16x16x32_bf16(af[rt], bfr[nt], acc[rt][nt], 0, 0, 0);
    __syncthreads();
  }

#pragma unroll
  for (int rt = 0; rt < 4; ++rt)
#pragma unroll
    for (int nt = 0; nt < 4; ++nt) {
      const int col = n0 + wc * 64 + nt * 16 + c;
#pragma unroll
      for (int r = 0; r < 4; ++r) {
        const int m = m0 + wr * 64 + rt * 16 + g * 4 + r;
        const float v = acc[rt][nt][r];
        if (MODE == 0) {
          const int sec = col >> 9, hh = (col >> 6) & 7, dh = col & 63;
          const int bh = (m >> 12) * 8 + hh, n = m & 4095;
          const size_t idx = (size_t)(bh * 4096 + n) * 64 + dh;
          if (sec == 0)      Qb[idx] = f2bf(v * 0.18033688011112042f); // 1/8*log2(e)
          else if (sec == 1) Kb[idx] = f2bf(v);
          else               Vb[idx] = f2bf(v);
        } else {
          Cout[(size_t)m * 512 + col] = v + bias[col];
        }
      }
    }
}

// ------------------------------------------- V transpose: [bh][n][64] -> [bh][64][n]
__global__ __launch_bounds__(256) void vtrans_kernel(
    const unsigned short* __restrict__ Vb, unsigned short* __restrict__ Vtb) {
  __shared__ unsigned short tl[64][72];          // 72: 16B-aligned rows, bank-spread
  const int tid = threadIdx.x;
  const int bh = blockIdx.x >> 6, nt = blockIdx.x & 63;
  const int n0 = nt * 64;
  const unsigned short* src = Vb + ((size_t)bh * 4096 + n0) * 64;
#pragma unroll
  for (int h = 0; h < 2; ++h) {
    const int r = (tid >> 3) + h * 32;
    const int c0 = (tid & 7) * 8;
    *(short8v*)&tl[r][c0] = *(const short8v*)(src + r * 64 + c0);
  }
  __syncthreads();
#pragma unroll
  for (int h = 0; h < 2; ++h) {
    const int d = (tid >> 3) + h * 32;
    const int m0 = (tid & 7) * 8;
    unsigned short tmp[8];
#pragma unroll
    for (int i = 0; i < 8; ++i) tmp[i] = tl[m0 + i][d];
    *(short8v*)(Vtb + ((size_t)bh * 64 + d) * 4096 + n0 + m0) = *(const short8v*)&tmp[0];
  }
}

// ---------------------------------------------------------------- attention
// grid 1024 = chunk*512 + qb*16 + bh. Split-KV x2 (2048 keys per block).
// 4 waves x 32 q-rows, KV tile 64, no-max softmax exp2(S) (scale folded into Q).
// Swapped QK^T: S^T = mfma(K, Q) -> lane holds q=c, keys kt*16+g*4..+3 packed
// as 2 u32 bf16-pairs; PV A-frags assembled IN-REGISTER via
// v_permlane32_swap + v_permlane16_swap (no LDS round-trip, no bank conflicts).
// Rowsums via mfma(P, ones). Partial O (unnormalized, fp32) + rowsum to global.
__global__ __launch_bounds__(256, 4) void attn_kernel(
    const unsigned short* __restrict__ Qb, const unsigned short* __restrict__ Kb,
    const unsigned short* __restrict__ Vtb, float* __restrict__ Opart,
    float* __restrict__ spart) {
  __shared__ short Kbuf[2][64 * 64];
  __shared__ short Vbuf[2][64 * 64];
  const int tid = threadIdx.x;
  const int w = tid >> 6, l = tid & 63;
  const int g = l >> 4, c = l & 15, c7 = l & 7;
  const int bh = blockIdx.x & 15;
  const int qb = (blockIdx.x >> 4) & 31;        // 0..31
  const int chunk = blockIdx.x >> 9;            // 0..1
  const int q0 = qb * 128 + w * 32;
  const unsigned short* Qp = Qb + (size_t)(bh * 4096 + q0) * 64;
  const unsigned short* Kp = Kb + (size_t)bh * 4096 * 64;
  const unsigned short* Vp = Vtb + (size_t)bh * 64 * 4096;

  // Q as B-fragments: lane holds Q[q = qt*16+c][d = kk*32 + g*8 + j] (pre-scaled)
  bf16x8 qf[2][2];
#pragma unroll
  for (int qt = 0; qt < 2; ++qt)
#pragma unroll
    for (int kk = 0; kk < 2; ++kk)
      qf[qt][kk] = __builtin_bit_cast(bf16x8,
          *(const short8v*)(Qp + (size_t)(qt * 16 + c) * 64 + kk * 32 + g * 8));

  // ones B-fragment for rowsum-by-MFMA
  short8v ones_s;
#pragma unroll
  for (int i = 0; i < 8; ++i) ones_s[i] = (short)0x3f80;  // bf16 1.0
  const bf16x8 ones = __builtin_bit_cast(bf16x8, ones_s);

  f32x4 O[2][4] = {};
  f32x4 osum[2] = {};

  auto STAGEKV = [&](int buf, int t) {         // t in [0,32)
    const int kv0 = (chunk * 32 + t) * 64;
#pragma unroll
    for (int j = 0; j < 2; ++j) {
      const int row = w * 16 + j * 8 + (l >> 3);
      const int gk = (l & 7) ^ (row & 7);        // pre-swizzled source
      gld16(&Kbuf[buf][(w * 16 + j * 8) * 64], Kp + (size_t)(kv0 + row) * 64 + gk * 8);
      gld16(&Vbuf[buf][(w * 16 + j * 8) * 64], Vp + (size_t)row * 4096 + kv0 + gk * 8);
    }
  };

  STAGEKV(0, 0);
  __syncthreads();

  for (int t = 0; t < 32; ++t) {
    const int buf = t & 1;
    if (t + 1 < 32) STAGEKV(buf ^ 1, t + 1);

    // ---- swapped QK^T: S^T[key][q] = K . Q^T, exp2, pack to u32 bf16-pairs.
    // xu[qt][kt][0] = keys kt*16+g*4+{0,1}; [1] = +{2,3}   (for q = qt*16+c)
    unsigned xu[2][4][2];
#pragma unroll
    for (int kt = 0; kt < 4; ++kt) {
      const int krow = kt * 16 + c;
      bf16x8 kf0 = __builtin_bit_cast(bf16x8,
          *(const short8v*)&Kbuf[buf][krow * 64 + ((0 * 4 + g) ^ c7) * 8]);
      bf16x8 kf1 = __builtin_bit_cast(bf16x8,
          *(const short8v*)&Kbuf[buf][krow * 64 + ((1 * 4 + g) ^ c7) * 8]);
#pragma unroll
      for (int qt = 0; qt < 2; ++qt) {
        f32x4 S = {};
        S = __builtin_amdgcn_mfma_f32_16x16x32_bf16(kf0, qf[qt][0], S, 0, 0, 0);
        S = __builtin_amdgcn_mfma_f32_16x16x32_bf16(kf1, qf[qt][1], S, 0, 0, 0);
        const float p0 = exp2f(S[0]);
        const float p1 = exp2f(S[1]);
        const float p2 = exp2f(S[2]);
        const float p3 = exp2f(S[3]);
        unsigned u0, u1;
        asm("v_cvt_pk_bf16_f32 %0, %1, %2" : "=v"(u0) : "v"(p0), "v"(p1));
        asm("v_cvt_pk_bf16_f32 %0, %1, %2" : "=v"(u1) : "v"(p2), "v"(p3));
        xu[qt][kt][0] = u0;
        xu[qt][kt][1] = u1;
      }
    }

    // ---- PV with in-register P: per (kk): A-frag(lane g,c) needs
    // P[q=c][keys kk*32+g*8..+7] = quads (kt=2kk..2kk+1, g_src=0..3).
    // swap32 then swap16 on the (kt_lo, kt_hi) u-pairs lands exactly that.
#pragma unroll
    for (int kk = 0; kk < 2; ++kk) {
      bf16x8 vf[4];
#pragma unroll
      for (int nt = 0; nt < 4; ++nt) {
        const int vrow = nt * 16 + c;
        vf[nt] = __builtin_bit_cast(bf16x8,
            *(const short8v*)&Vbuf[buf][vrow * 64 + (((kk * 4 + g) ^ c7) * 8)]);
      }
#pragma unroll
      for (int rt = 0; rt < 2; ++rt) {
        unsigned a0 = xu[rt][2 * kk][0], a2 = xu[rt][2 * kk + 1][0];
        asm("v_permlane32_swap_b32 %0, %1" : "+v"(a0), "+v"(a2));
        asm("v_permlane16_swap_b32 %0, %1" : "+v"(a0), "+v"(a2));
        unsigned a1 = xu[rt][2 * kk][1], a3 = xu[rt][2 * kk + 1][1];
        asm("v_permlane32_swap_b32 %0, %1" : "+v"(a1), "+v"(a3));
        asm("v_permlane16_swap_b32 %0, %1" : "+v"(a1), "+v"(a3));
        uint4v av; av[0] = a0; av[1] = a1; av[2] = a2; av[3] = a3;
        const bf16x8 pa = __builtin_bit_cast(bf16x8, av);
        __builtin_amdgcn_s_setprio(1);
        osum[rt] = __builtin_amdgcn_mfma_f32_16x16x32_bf16(pa, ones, osum[rt], 0, 0, 0);
#pragma unroll
        for (int nt = 0; nt < 4; ++nt)
          O[rt][nt] = __builtin_amdgcn_mfma_f32_16x16x32_bf16(pa, vf[nt], O[rt][nt], 0, 0, 0);
        __builtin_amdgcn_s_setprio(0);
      }
    }
    __syncthreads();
  }

  // ---- write partial O (unnormalized fp32) + rowsums
  float* Op = Opart + ((size_t)(chunk * 16 + bh) * 4096 + q0) * 64;
#pragma unroll
  for (int rt = 0; rt < 2; ++rt) {
#pragma unroll
    for (int nt = 0; nt < 4; ++nt)
#pragma unroll
      for (int r = 0; r < 4; ++r)
        Op[(size_t)(rt * 16 + g * 4 + r) * 64 + nt * 16 + c] = O[rt][nt][r];
    if (c == 0) {
#pragma unroll
      for (int r = 0; r < 4; ++r)
        spart[(size_t)(chunk * 16 + bh) * 4096 + q0 + rt * 16 + g * 4 + r] = osum[rt][r];
    }
  }
}

// ------------------------------------------- combine: (O0+O1)/(s0+s1) -> bf16
__global__ __launch_bounds__(256) void combine_kernel(
    const float* __restrict__ Opart, const float* __restrict__ spart,
    unsigned short* __restrict__ attnb) {
  const size_t CH = (size_t)16 * 4096 * 64;      // chunk stride (elems)
  const int gid = blockIdx.x * 256 + threadIdx.x;
  const size_t i = (size_t)gid * 4;              // into [16][4096][64]
  const int d = (int)(i & 63);
  const int bhq = (int)(i >> 6);                 // bh*4096 + q
  const f32x4 o0 = *(const f32x4*)(Opart + i);
  const f32x4 o1 = *(const f32x4*)(Opart + CH + i);
  const float inv = 1.0f / (spart[bhq] + spart[bhq + 16 * 4096]);
  const int bh = bhq >> 12, q = bhq & 4095;
  const int tok = (bh >> 3) * 4096 + q;
  const int col = (bh & 7) * 64 + d;
  unsigned u0, u1;
  const float r0 = (o0[0] + o1[0]) * inv, r1 = (o0[1] + o1[1]) * inv;
  const float r2 = (o0[2] + o1[2]) * inv, r3 = (o0[3] + o1[3]) * inv;
  u0 = (unsigned)f2bf(r0) | ((unsigned)f2bf(r1) << 16);
  u1 = (unsigned)f2bf(r2) | ((unsigned)f2bf(r3) << 16);
  *(uint2*)(attnb + (size_t)tok * 512 + col) = make_uint2(u0, u1);
}

// ---------------------------------------------------------------- launch
extern "C" void kernel_launch(void* const* d_in, const int* in_sizes, int n_in,
                              void* d_out, int out_size, void* d_ws, size_t ws_size,
                              hipStream_t stream) {
  (void)in_sizes; (void)n_in; (void)out_size; (void)ws_size;
  const float* x     = (const float*)d_in[0];
  const float* gamma = (const float*)d_in[1];
  const float* beta  = (const float*)d_in[2];
  const float* wqkv  = (const float*)d_in[3];
  const float* wout  = (const float*)d_in[4];
  const float* bout  = (const float*)d_in[5];
  float* out = (float*)d_out;

  char* ws = (char*)d_ws;
  size_t off = 0;
  auto alloc = [&](size_t bytes) {
    void* p = ws + off;
    off += (bytes + 255) & ~(size_t)255;
    return p;
  };
  unsigned*       xnb   = (unsigned*)alloc((size_t)MTOK * DIMF * 2);
  unsigned short* wqkvT = (unsigned short*)alloc((size_t)1536 * 512 * 2);
  unsigned short* woT   = (unsigned short*)alloc((size_t)512 * 512 * 2);
  unsigned short* Qbuf  = (unsigned short*)alloc((size_t)NBH * NSEQ * DHEAD * 2);
  unsigned short* Kb    = (unsigned short*)alloc((size_t)NBH * NSEQ * DHEAD * 2);
  unsigned short* Vtb   = (unsigned short*)alloc((size_t)NBH * NSEQ * DHEAD * 2);
  unsigned short* attnb = (unsigned short*)alloc((size_t)MTOK * DIMF * 2);
  float*          Opart = (float*)alloc((size_t)2 * NBH * NSEQ * DHEAD * 4);
  float*          spart = (float*)alloc((size_t)2 * NBH * NSEQ * 4);
  unsigned short* Vb    = attnb;   // alias: Vb consumed by vtrans before combine writes attnb

  ln_kernel<<<dim3(MTOK), dim3(256), 0, stream>>>(x, gamma, beta, xnb);
  wprep_kernel<<<dim3(4096), dim3(256), 0, stream>>>(wqkv, wout, wqkvT, woT);
  gemm_kernel<0><<<dim3(64 * 12), dim3(256), 0, stream>>>(
      (const unsigned short*)xnb, wqkvT, Qbuf, Kb, Vb, nullptr, nullptr, 1536);
  vtrans_kernel<<<dim3(NBH * 64), dim3(256), 0, stream>>>(Vb, Vtb);
  attn_kernel<<<dim3(1024), dim3(256), 0, stream>>>(Qbuf, Kb, Vtb, Opart, spart);
  combine_kernel<<<dim3(4096), dim3(256), 0, stream>>>(Opart, spart, attnb);
  gemm_kernel<1><<<dim3(64 * 4), dim3(256), 0, stream>>>(
      attnb, woT, nullptr, nullptr, nullptr, bout, out, 512);
}

// Round 8
// 212.747 us; speedup vs baseline: 1.2995x; 1.0833x over previous
//
#include <hip/hip_runtime.h>
#include <stdint.h>

// Problem constants
#define NBATCH 2
#define NSEQ   4096
#define DIMF   512
#define HEADS  8
#define DHEAD  64
#define MTOK   (NBATCH*NSEQ)      // 8192 tokens
#define NBH    (NBATCH*HEADS)     // 16 (b,h) pairs

typedef __bf16 bf16x8 __attribute__((ext_vector_type(8)));
typedef __bf16 bf16x2 __attribute__((ext_vector_type(2)));
typedef float  f32x4  __attribute__((ext_vector_type(4)));
typedef float  f32x2v __attribute__((ext_vector_type(2)));
typedef short  short8v __attribute__((ext_vector_type(8)));
typedef unsigned uint4v __attribute__((ext_vector_type(4)));

__device__ __forceinline__ unsigned short f2bf(float f) {
  unsigned x = __builtin_bit_cast(unsigned, f);
  x += 0x7fffu + ((x >> 16) & 1u);          // round-to-nearest-even
  return (unsigned short)(x >> 16);
}

// Packed f32x2 -> bf16x2 via compiler fptrunc (gfx950: v_cvt_pk_bf16_f32).
// r5-r7 lesson: do NOT consume a v_exp_f32 result inside an INLINEASM block —
// the TRANS->consumer wait-state is only inserted for compiler-visible
// consumers. This keeps the whole exp->pack chain in compiler-generated code.
__device__ __forceinline__ unsigned pack2bf(float a, float b) {
  f32x2v v; v[0] = a; v[1] = b;
  bf16x2 r = __builtin_convertvector(v, bf16x2);
  return __builtin_bit_cast(unsigned, r);
}

// async global->LDS, 16B per lane. LDS dest is wave-uniform base (+lane*16 implicit).
__device__ __forceinline__ void gld16(void* lds, const void* g) {
  __builtin_amdgcn_global_load_lds(
      (const __attribute__((address_space(1))) unsigned*)g,
      (__attribute__((address_space(3))) unsigned*)lds, 16, 0, 0);
}

// ---------------------------------------------------------------- LayerNorm
__global__ __launch_bounds__(256) void ln_kernel(
    const float* __restrict__ x, const float* __restrict__ gamma,
    const float* __restrict__ beta, unsigned* __restrict__ xnb) {
  const int row = blockIdx.x;
  const int t = threadIdx.x;
  const float2 v = *(const float2*)(x + (size_t)row * DIMF + t * 2);
  float s1 = v.x + v.y;
  float s2 = v.x * v.x + v.y * v.y;
#pragma unroll
  for (int m = 1; m < 64; m <<= 1) { s1 += __shfl_xor(s1, m); s2 += __shfl_xor(s2, m); }
  __shared__ float ls1[4], ls2[4];
  const int w = t >> 6;
  if ((t & 63) == 0) { ls1[w] = s1; ls2[w] = s2; }
  __syncthreads();
  s1 = ls1[0] + ls1[1] + ls1[2] + ls1[3];
  s2 = ls2[0] + ls2[1] + ls2[2] + ls2[3];
  const float mu  = s1 * (1.0f / 512.0f);
  const float var = s2 * (1.0f / 512.0f) - mu * mu;
  const float rs  = 1.0f / sqrtf(var + 1e-5f);
  const float2 g2 = *(const float2*)(gamma + t * 2);
  const float2 b2 = *(const float2*)(beta + t * 2);
  const float a0 = (v.x - mu) * rs * g2.x + b2.x;
  const float a1 = (v.y - mu) * rs * g2.y + b2.y;
  xnb[(size_t)row * 256 + t] = (unsigned)f2bf(a0) | ((unsigned)f2bf(a1) << 16);
}

// ------------------------------------------- weight cast + transpose (once/call)
__global__ __launch_bounds__(256) void wprep_kernel(
    const float* __restrict__ wqkv, const float* __restrict__ wout,
    unsigned short* __restrict__ wqkvT, unsigned short* __restrict__ woT) {
  const int tid = blockIdx.x * 256 + threadIdx.x;
  if (tid < 512 * 1536) {
    const int c = tid % 1536, k = tid / 1536;       // coalesced read
    wqkvT[c * 512 + k] = f2bf(wqkv[(size_t)k * 1536 + c]);
  } else {
    const int i = tid - 512 * 1536;
    const int c = i % 512, k = i / 512;
    woT[c * 512 + k] = f2bf(wout[(size_t)k * 512 + c]);
  }
}

// ---------------------------------------------------------------- GEMM
// C[M][Ncols] = A[M][512] * Bt[Ncols][512]^T, bf16 in, fp32 acc.
// MODE 0: scatter epilogue -> Qb (scaled by 1/8), Kb, Vb all [bh][n][64]
// MODE 1: fp32 epilogue -> Cout + bias
template <int MODE>
__global__ __launch_bounds__(256, 2) void gemm_kernel(
    const unsigned short* __restrict__ A, const unsigned short* __restrict__ Bt,
    unsigned short* __restrict__ Qb, unsigned short* __restrict__ Kb,
    unsigned short* __restrict__ Vb,
    const float* __restrict__ bias, float* __restrict__ Cout, int Ncols) {
  __shared__ short Ab[2][128 * 32];
  __shared__ short Bb[2][128 * 32];
  const int tid = threadIdx.x;
  const int w = tid >> 6, l = tid & 63;
  const int g = l >> 4, c = l & 15;
  const int nbn = Ncols >> 7;
  const int mb = blockIdx.x / nbn, nb = blockIdx.x % nbn;
  const int m0 = mb * 128, n0 = nb * 128;
  const int wr = w >> 1, wc = w & 1;

  f32x4 acc[4][4] = {};

  auto STAGE = [&](int buf, int kt) {
    const int k0 = kt * 32;
#pragma unroll
    for (int j = 0; j < 2; ++j) {
      const int row = w * 32 + j * 16 + (l >> 2);
      const int gk = (l & 3) ^ ((row >> 1) & 3);   // pre-swizzled source
      gld16(&Ab[buf][(w * 32 + j * 16) * 32], A + (size_t)(m0 + row) * 512 + k0 + gk * 8);
      gld16(&Bb[buf][(w * 32 + j * 16) * 32], Bt + (size_t)(n0 + row) * 512 + k0 + gk * 8);
    }
  };

  STAGE(0, 0);
  __syncthreads();

  for (int kt = 0; kt < 16; ++kt) {
    const int buf = kt & 1;
    if (kt + 1 < 16) STAGE(buf ^ 1, kt + 1);
    bf16x8 af[4], bfr[4];
#pragma unroll
    for (int rt = 0; rt < 4; ++rt) {
      const int row = wr * 64 + rt * 16 + c;
      const int slot = g ^ ((row >> 1) & 3);
      af[rt] = __builtin_bit_cast(bf16x8, *(const short8v*)&Ab[buf][row * 32 + slot * 8]);
    }
#pragma unroll
    for (int nt = 0; nt < 4; ++nt) {
      const int row = wc * 64 + nt * 16 + c;
      const int slot = g ^ ((row >> 1) & 3);
      bfr[nt] = __builtin_bit_cast(bf16x8, *(const short8v*)&Bb[buf][row * 32 + slot * 8]);
    }
#pragma unroll
    for (int rt = 0; rt < 4; ++rt)
#pragma unroll
      for (int nt = 0; nt < 4; ++nt)
        acc[rt][nt] = __builtin_amdgcn_mfma_f32_16x16x32_bf16(af[rt], bfr[nt], acc[rt][nt], 0, 0, 0);
    __syncthreads();
  }

#pragma unroll
  for (int rt = 0; rt < 4; ++rt)
#pragma unroll
    for (int nt = 0; nt < 4; ++nt) {
      const int col = n0 + wc * 64 + nt * 16 + c;
#pragma unroll
      for (int r = 0; r < 4; ++r) {
        const int m = m0 + wr * 64 + rt * 16 + g * 4 + r;
        const float v = acc[rt][nt][r];
        if (MODE == 0) {
          const int sec = col >> 9, hh = (col >> 6) & 7, dh = col & 63;
          const int bh = (m >> 12) * 8 + hh, n = m & 4095;
          const size_t idx = (size_t)(bh * 4096 + n) * 64 + dh;
          if (sec == 0)      Qb[idx] = f2bf(v * 0.125f);  // fold 1/sqrt(d); exact pow2
          else if (sec == 1) Kb[idx] = f2bf(v);
          else               Vb[idx] = f2bf(v);
        } else {
          Cout[(size_t)m * 512 + col] = v + bias[col];
        }
      }
    }
}

// ------------------------------------------- V transpose: [bh][n][64] -> [bh][64][n]
__global__ __launch_bounds__(256) void vtrans_kernel(
    const unsigned short* __restrict__ Vb, unsigned short* __restrict__ Vtb) {
  __shared__ unsigned short tl[64][72];          // 72: 16B-aligned rows, bank-spread
  const int tid = threadIdx.x;
  const int bh = blockIdx.x >> 6, nt = blockIdx.x & 63;
  const int n0 = nt * 64;
  const unsigned short* src = Vb + ((size_t)bh * 4096 + n0) * 64;
#pragma unroll
  for (int h = 0; h < 2; ++h) {
    const int r = (tid >> 3) + h * 32;
    const int c0 = (tid & 7) * 8;
    *(short8v*)&tl[r][c0] = *(const short8v*)(src + r * 64 + c0);
  }
  __syncthreads();
#pragma unroll
  for (int h = 0; h < 2; ++h) {
    const int d = (tid >> 3) + h * 32;
    const int m0 = (tid & 7) * 8;
    unsigned short tmp[8];
#pragma unroll
    for (int i = 0; i < 8; ++i) tmp[i] = tl[m0 + i][d];
    *(short8v*)(Vtb + ((size_t)bh * 64 + d) * 4096 + n0 + m0) = *(const short8v*)&tmp[0];
  }
}

// ---------------------------------------------------------------- attention
// grid 1024 = chunk*512 + qb*16 + bh. Split-KV x2 (2048 keys per block).
// 4 waves x 32 q-rows, KV tile 64, no-max softmax P = __expf(S), S = q.k/8
// (|S| <~ 8, no max-subtraction needed). Swapped QK^T: S^T = mfma(K, Q) ->
// lane holds q=c, keys kt*16+g*4..+3, packed to bf16 pairs by compiler
// convertvector (v_cvt_pk); PV A-frags assembled IN-REGISTER via
// v_permlane32_swap + v_permlane16_swap (no LDS round-trip, no bank conflicts).
// Rowsums via mfma(P, ones). Partial O (unnormalized, fp32) + rowsum to global.
__global__ __launch_bounds__(256, 4) void attn_kernel(
    const unsigned short* __restrict__ Qb, const unsigned short* __restrict__ Kb,
    const unsigned short* __restrict__ Vtb, float* __restrict__ Opart,
    float* __restrict__ spart) {
  __shared__ short Kbuf[2][64 * 64];
  __shared__ short Vbuf[2][64 * 64];
  const int tid = threadIdx.x;
  const int w = tid >> 6, l = tid & 63;
  const int g = l >> 4, c = l & 15, c7 = l & 7;
  const int bh = blockIdx.x & 15;
  const int qb = (blockIdx.x >> 4) & 31;        // 0..31
  const int chunk = blockIdx.x >> 9;            // 0..1
  const int q0 = qb * 128 + w * 32;
  const unsigned short* Qp = Qb + (size_t)(bh * 4096 + q0) * 64;
  const unsigned short* Kp = Kb + (size_t)bh * 4096 * 64;
  const unsigned short* Vp = Vtb + (size_t)bh * 64 * 4096;

  // Q as B-fragments: lane holds Q[q = qt*16+c][d = kk*32 + g*8 + j] (pre-scaled)
  bf16x8 qf[2][2];
#pragma unroll
  for (int qt = 0; qt < 2; ++qt)
#pragma unroll
    for (int kk = 0; kk < 2; ++kk)
      qf[qt][kk] = __builtin_bit_cast(bf16x8,
          *(const short8v*)(Qp + (size_t)(qt * 16 + c) * 64 + kk * 32 + g * 8));

  // ones B-fragment for rowsum-by-MFMA
  short8v ones_s;
#pragma unroll
  for (int i = 0; i < 8; ++i) ones_s[i] = (short)0x3f80;  // bf16 1.0
  const bf16x8 ones = __builtin_bit_cast(bf16x8, ones_s);

  f32x4 O[2][4] = {};
  f32x4 osum[2] = {};

  auto STAGEKV = [&](int buf, int t) {         // t in [0,32)
    const int kv0 = (chunk * 32 + t) * 64;
#pragma unroll
    for (int j = 0; j < 2; ++j) {
      const int row = w * 16 + j * 8 + (l >> 3);
      const int gk = (l & 7) ^ (row & 7);        // pre-swizzled source
      gld16(&Kbuf[buf][(w * 16 + j * 8) * 64], Kp + (size_t)(kv0 + row) * 64 + gk * 8);
      gld16(&Vbuf[buf][(w * 16 + j * 8) * 64], Vp + (size_t)row * 4096 + kv0 + gk * 8);
    }
  };

  STAGEKV(0, 0);
  __syncthreads();

  for (int t = 0; t < 32; ++t) {
    const int buf = t & 1;
    if (t + 1 < 32) STAGEKV(buf ^ 1, t + 1);

    // ---- swapped QK^T: S^T[key][q] = K . Q^T, exp, pack to u32 bf16-pairs.
    // xu[qt][kt][0] = keys kt*16+g*4+{0,1}; [1] = +{2,3}   (for q = qt*16+c)
    unsigned xu[2][4][2];
#pragma unroll
    for (int kt = 0; kt < 4; ++kt) {
      const int krow = kt * 16 + c;
      bf16x8 kf0 = __builtin_bit_cast(bf16x8,
          *(const short8v*)&Kbuf[buf][krow * 64 + ((0 * 4 + g) ^ c7) * 8]);
      bf16x8 kf1 = __builtin_bit_cast(bf16x8,
          *(const short8v*)&Kbuf[buf][krow * 64 + ((1 * 4 + g) ^ c7) * 8]);
#pragma unroll
      for (int qt = 0; qt < 2; ++qt) {
        f32x4 S = {};
        S = __builtin_amdgcn_mfma_f32_16x16x32_bf16(kf0, qf[qt][0], S, 0, 0, 0);
        S = __builtin_amdgcn_mfma_f32_16x16x32_bf16(kf1, qf[qt][1], S, 0, 0, 0);
        const float p0 = __expf(S[0]);
        const float p1 = __expf(S[1]);
        const float p2 = __expf(S[2]);
        const float p3 = __expf(S[3]);
        xu[qt][kt][0] = pack2bf(p0, p1);       // compiler-visible TRANS consumer
        xu[qt][kt][1] = pack2bf(p2, p3);
      }
    }

    // ---- PV with in-register P: per (kk): A-frag(lane g,c) needs
    // P[q=c][keys kk*32+g*8..+7] = quads (kt=2kk..2kk+1, g_src=0..3).
    // swap32 then swap16 on the (kt_lo, kt_hi) u-pairs lands exactly that.
#pragma unroll
    for (int kk = 0; kk < 2; ++kk) {
      bf16x8 vf[4];
#pragma unroll
      for (int nt = 0; nt < 4; ++nt) {
        const int vrow = nt * 16 + c;
        vf[nt] = __builtin_bit_cast(bf16x8,
            *(const short8v*)&Vbuf[buf][vrow * 64 + (((kk * 4 + g) ^ c7) * 8)]);
      }
#pragma unroll
      for (int rt = 0; rt < 2; ++rt) {
        unsigned a0 = xu[rt][2 * kk][0], a2 = xu[rt][2 * kk + 1][0];
        asm("v_permlane32_swap_b32 %0, %1" : "+v"(a0), "+v"(a2));
        asm("v_permlane16_swap_b32 %0, %1" : "+v"(a0), "+v"(a2));
        unsigned a1 = xu[rt][2 * kk][1], a3 = xu[rt][2 * kk + 1][1];
        asm("v_permlane32_swap_b32 %0, %1" : "+v"(a1), "+v"(a3));
        asm("v_permlane16_swap_b32 %0, %1" : "+v"(a1), "+v"(a3));
        uint4v av; av[0] = a0; av[1] = a1; av[2] = a2; av[3] = a3;
        const bf16x8 pa = __builtin_bit_cast(bf16x8, av);
        __builtin_amdgcn_s_setprio(1);
        osum[rt] = __builtin_amdgcn_mfma_f32_16x16x32_bf16(pa, ones, osum[rt], 0, 0, 0);
#pragma unroll
        for (int nt = 0; nt < 4; ++nt)
          O[rt][nt] = __builtin_amdgcn_mfma_f32_16x16x32_bf16(pa, vf[nt], O[rt][nt], 0, 0, 0);
        __builtin_amdgcn_s_setprio(0);
      }
    }
    __syncthreads();
  }

  // ---- write partial O (unnormalized fp32) + rowsums
  float* Op = Opart + ((size_t)(chunk * 16 + bh) * 4096 + q0) * 64;
#pragma unroll
  for (int rt = 0; rt < 2; ++rt) {
#pragma unroll
    for (int nt = 0; nt < 4; ++nt)
#pragma unroll
      for (int r = 0; r < 4; ++r)
        Op[(size_t)(rt * 16 + g * 4 + r) * 64 + nt * 16 + c] = O[rt][nt][r];
    if (c == 0) {
#pragma unroll
      for (int r = 0; r < 4; ++r)
        spart[(size_t)(chunk * 16 + bh) * 4096 + q0 + rt * 16 + g * 4 + r] = osum[rt][r];
    }
  }
}

// ------------------------------------------- combine: (O0+O1)/(s0+s1) -> bf16
__global__ __launch_bounds__(256) void combine_kernel(
    const float* __restrict__ Opart, const float* __restrict__ spart,
    unsigned short* __restrict__ attnb) {
  const size_t CH = (size_t)16 * 4096 * 64;      // chunk stride (elems)
  const int gid = blockIdx.x * 256 + threadIdx.x;
  const size_t i = (size_t)gid * 4;              // into [16][4096][64]
  const int d = (int)(i & 63);
  const int bhq = (int)(i >> 6);                 // bh*4096 + q
  const f32x4 o0 = *(const f32x4*)(Opart + i);
  const f32x4 o1 = *(const f32x4*)(Opart + CH + i);
  const float inv = 1.0f / (spart[bhq] + spart[bhq + 16 * 4096]);
  const int bh = bhq >> 12, q = bhq & 4095;
  const int tok = (bh >> 3) * 4096 + q;
  const int col = (bh & 7) * 64 + d;
  unsigned u0, u1;
  const float r0 = (o0[0] + o1[0]) * inv, r1 = (o0[1] + o1[1]) * inv;
  const float r2 = (o0[2] + o1[2]) * inv, r3 = (o0[3] + o1[3]) * inv;
  u0 = (unsigned)f2bf(r0) | ((unsigned)f2bf(r1) << 16);
  u1 = (unsigned)f2bf(r2) | ((unsigned)f2bf(r3) << 16);
  *(uint2*)(attnb + (size_t)tok * 512 + col) = make_uint2(u0, u1);
}

// ---------------------------------------------------------------- launch
extern "C" void kernel_launch(void* const* d_in, const int* in_sizes, int n_in,
                              void* d_out, int out_size, void* d_ws, size_t ws_size,
                              hipStream_t stream) {
  (void)in_sizes; (void)n_in; (void)out_size; (void)ws_size;
  const float* x     = (const float*)d_in[0];
  const float* gamma = (const float*)d_in[1];
  const float* beta  = (const float*)d_in[2];
  const float* wqkv  = (const float*)d_in[3];
  const float* wout  = (const float*)d_in[4];
  const float* bout  = (const float*)d_in[5];
  float* out = (float*)d_out;

  char* ws = (char*)d_ws;
  size_t off = 0;
  auto alloc = [&](size_t bytes) {
    void* p = ws + off;
    off += (bytes + 255) & ~(size_t)255;
    return p;
  };
  unsigned*       xnb   = (unsigned*)alloc((size_t)MTOK * DIMF * 2);
  unsigned short* wqkvT = (unsigned short*)alloc((size_t)1536 * 512 * 2);
  unsigned short* woT   = (unsigned short*)alloc((size_t)512 * 512 * 2);
  unsigned short* Qbuf  = (unsigned short*)alloc((size_t)NBH * NSEQ * DHEAD * 2);
  unsigned short* Kb    = (unsigned short*)alloc((size_t)NBH * NSEQ * DHEAD * 2);
  unsigned short* Vtb   = (unsigned short*)alloc((size_t)NBH * NSEQ * DHEAD * 2);
  unsigned short* attnb = (unsigned short*)alloc((size_t)MTOK * DIMF * 2);
  float*          Opart = (float*)alloc((size_t)2 * NBH * NSEQ * DHEAD * 4);
  float*          spart = (float*)alloc((size_t)2 * NBH * NSEQ * 4);
  unsigned short* Vb    = attnb;   // alias: Vb consumed by vtrans before combine writes attnb

  ln_kernel<<<dim3(MTOK), dim3(256), 0, stream>>>(x, gamma, beta, xnb);
  wprep_kernel<<<dim3(4096), dim3(256), 0, stream>>>(wqkv, wout, wqkvT, woT);
  gemm_kernel<0><<<dim3(64 * 12), dim3(256), 0, stream>>>(
      (const unsigned short*)xnb, wqkvT, Qbuf, Kb, Vb, nullptr, nullptr, 1536);
  vtrans_kernel<<<dim3(NBH * 64), dim3(256), 0, stream>>>(Vb, Vtb);
  attn_kernel<<<dim3(1024), dim3(256), 0, stream>>>(Qbuf, Kb, Vtb, Opart, spart);
  combine_kernel<<<dim3(4096), dim3(256), 0, stream>>>(Opart, spart, attnb);
  gemm_kernel<1><<<dim3(64 * 4), dim3(256), 0, stream>>>(
      attnb, woT, nullptr, nullptr, nullptr, bout, out, 512);
}

// Round 9
// 209.989 us; speedup vs baseline: 1.3166x; 1.0131x over previous
//
#include <hip/hip_runtime.h>
#include <stdint.h>

// Problem constants
#define NBATCH 2
#define NSEQ   4096
#define DIMF   512
#define HEADS  8
#define DHEAD  64
#define MTOK   (NBATCH*NSEQ)      // 8192 tokens
#define NBH    (NBATCH*HEADS)     // 16 (b,h) pairs

typedef __bf16 bf16x8 __attribute__((ext_vector_type(8)));
typedef __bf16 bf16x2 __attribute__((ext_vector_type(2)));
typedef float  f32x4  __attribute__((ext_vector_type(4)));
typedef float  f32x2v __attribute__((ext_vector_type(2)));
typedef short  short8v __attribute__((ext_vector_type(8)));
typedef unsigned uint4v __attribute__((ext_vector_type(4)));

__device__ __forceinline__ unsigned short f2bf(float f) {
  unsigned x = __builtin_bit_cast(unsigned, f);
  x += 0x7fffu + ((x >> 16) & 1u);          // round-to-nearest-even
  return (unsigned short)(x >> 16);
}

// Packed f32x2 -> bf16x2 via compiler fptrunc (gfx950: v_cvt_pk_bf16_f32).
// r5-r7 lesson: do NOT consume a v_exp_f32 result inside an INLINEASM block —
// the TRANS->consumer wait-state is only inserted for compiler-visible
// consumers. This keeps the whole exp->pack chain in compiler-generated code.
__device__ __forceinline__ unsigned pack2bf(float a, float b) {
  f32x2v v; v[0] = a; v[1] = b;
  bf16x2 r = __builtin_convertvector(v, bf16x2);
  return __builtin_bit_cast(unsigned, r);
}

// async global->LDS, 16B per lane. LDS dest is wave-uniform base (+lane*16 implicit).
__device__ __forceinline__ void gld16(void* lds, const void* g) {
  __builtin_amdgcn_global_load_lds(
      (const __attribute__((address_space(1))) unsigned*)g,
      (__attribute__((address_space(3))) unsigned*)lds, 16, 0, 0);
}

// ---------------------------------------------------------------- LayerNorm
__global__ __launch_bounds__(256) void ln_kernel(
    const float* __restrict__ x, const float* __restrict__ gamma,
    const float* __restrict__ beta, unsigned* __restrict__ xnb) {
  const int row = blockIdx.x;
  const int t = threadIdx.x;
  const float2 v = *(const float2*)(x + (size_t)row * DIMF + t * 2);
  float s1 = v.x + v.y;
  float s2 = v.x * v.x + v.y * v.y;
#pragma unroll
  for (int m = 1; m < 64; m <<= 1) { s1 += __shfl_xor(s1, m); s2 += __shfl_xor(s2, m); }
  __shared__ float ls1[4], ls2[4];
  const int w = t >> 6;
  if ((t & 63) == 0) { ls1[w] = s1; ls2[w] = s2; }
  __syncthreads();
  s1 = ls1[0] + ls1[1] + ls1[2] + ls1[3];
  s2 = ls2[0] + ls2[1] + ls2[2] + ls2[3];
  const float mu  = s1 * (1.0f / 512.0f);
  const float var = s2 * (1.0f / 512.0f) - mu * mu;
  const float rs  = 1.0f / sqrtf(var + 1e-5f);
  const float2 g2 = *(const float2*)(gamma + t * 2);
  const float2 b2 = *(const float2*)(beta + t * 2);
  const float a0 = (v.x - mu) * rs * g2.x + b2.x;
  const float a1 = (v.y - mu) * rs * g2.y + b2.y;
  xnb[(size_t)row * 256 + t] = (unsigned)f2bf(a0) | ((unsigned)f2bf(a1) << 16);
}

// ------------------------------------------- weight cast + transpose (LDS-tiled)
// r8 post-mortem: old version did 2B scatter stores at 1KB stride (1.8M
// single-sector transactions, ~15 us). Now: 64x64 tiles via LDS (vtrans
// pattern) — coalesced fp32 reads, bf16 cast, coalesced 16B transposed writes.
// grid 256: blocks 0..191 = wqkv (8x24 tiles), 192..255 = wout (8x8 tiles).
__global__ __launch_bounds__(256) void wprep_kernel(
    const float* __restrict__ wqkv, const float* __restrict__ wout,
    unsigned short* __restrict__ wqkvT, unsigned short* __restrict__ woT) {
  __shared__ unsigned short tl[64][72];          // 72: pad, same as vtrans
  int bid = blockIdx.x;
  const float* src; unsigned short* dst; int C, k0, c0;
  if (bid < 192) {                                // wqkv: [512][1536]
    src = wqkv; dst = wqkvT; C = 1536;
    k0 = (bid / 24) * 64; c0 = (bid % 24) * 64;
  } else {                                        // wout: [512][512]
    bid -= 192; src = wout; dst = woT; C = 512;
    k0 = (bid / 8) * 64; c0 = (bid % 8) * 64;
  }
  const int tid = threadIdx.x;
  // load 64x64 fp32 tile (coalesced), cast -> bf16 LDS
  {
    const int r  = tid >> 2;                      // 0..63
    const int cc = (tid & 3) * 16;                // 16 floats/thread
#pragma unroll
    for (int i = 0; i < 4; ++i) {
      const float4 v = *(const float4*)(src + (size_t)(k0 + r) * C + c0 + cc + i * 4);
      tl[r][cc + i * 4 + 0] = f2bf(v.x);
      tl[r][cc + i * 4 + 1] = f2bf(v.y);
      tl[r][cc + i * 4 + 2] = f2bf(v.z);
      tl[r][cc + i * 4 + 3] = f2bf(v.w);
    }
  }
  __syncthreads();
  // transposed write: dst[c][k], 16B per lane (coalesced)
#pragma unroll
  for (int h = 0; h < 2; ++h) {
    const int crow = (tid >> 3) + h * 32;         // 0..63
    const int kk8  = (tid & 7) * 8;
    unsigned short tmp[8];
#pragma unroll
    for (int i = 0; i < 8; ++i) tmp[i] = tl[kk8 + i][crow];
    *(short8v*)(dst + (size_t)(c0 + crow) * 512 + k0 + kk8) = *(const short8v*)&tmp[0];
  }
}

// ---------------------------------------------------------------- GEMM
// C[M][Ncols] = A[M][512] * Bt[Ncols][512]^T, bf16 in, fp32 acc.
// MODE 0: scatter epilogue -> Qb (scaled by 1/8), Kb, Vb all [bh][n][64]
// MODE 1: fp32 epilogue -> Cout + bias
// launch_bounds(256,3): grid for MODE 0 is 768 = 3 blocks/CU; r7 exonerated
// this (r7 failed WITH (256,2) -> exp-asm boundary was the real r5/r6 cause).
template <int MODE>
__global__ __launch_bounds__(256, 3) void gemm_kernel(
    const unsigned short* __restrict__ A, const unsigned short* __restrict__ Bt,
    unsigned short* __restrict__ Qb, unsigned short* __restrict__ Kb,
    unsigned short* __restrict__ Vb,
    const float* __restrict__ bias, float* __restrict__ Cout, int Ncols) {
  __shared__ short Ab[2][128 * 32];
  __shared__ short Bb[2][128 * 32];
  const int tid = threadIdx.x;
  const int w = tid >> 6, l = tid & 63;
  const int g = l >> 4, c = l & 15;
  const int nbn = Ncols >> 7;
  const int mb = blockIdx.x / nbn, nb = blockIdx.x % nbn;
  const int m0 = mb * 128, n0 = nb * 128;
  const int wr = w >> 1, wc = w & 1;

  f32x4 acc[4][4] = {};

  auto STAGE = [&](int buf, int kt) {
    const int k0 = kt * 32;
#pragma unroll
    for (int j = 0; j < 2; ++j) {
      const int row = w * 32 + j * 16 + (l >> 2);
      const int gk = (l & 3) ^ ((row >> 1) & 3);   // pre-swizzled source
      gld16(&Ab[buf][(w * 32 + j * 16) * 32], A + (size_t)(m0 + row) * 512 + k0 + gk * 8);
      gld16(&Bb[buf][(w * 32 + j * 16) * 32], Bt + (size_t)(n0 + row) * 512 + k0 + gk * 8);
    }
  };

  STAGE(0, 0);
  __syncthreads();

  for (int kt = 0; kt < 16; ++kt) {
    const int buf = kt & 1;
    if (kt + 1 < 16) STAGE(buf ^ 1, kt + 1);
    bf16x8 af[4], bfr[4];
#pragma unroll
    for (int rt = 0; rt < 4; ++rt) {
      const int row = wr * 64 + rt * 16 + c;
      const int slot = g ^ ((row >> 1) & 3);
      af[rt] = __builtin_bit_cast(bf16x8, *(const short8v*)&Ab[buf][row * 32 + slot * 8]);
    }
#pragma unroll
    for (int nt = 0; nt < 4; ++nt) {
      const int row = wc * 64 + nt * 16 + c;
      const int slot = g ^ ((row >> 1) & 3);
      bfr[nt] = __builtin_bit_cast(bf16x8, *(const short8v*)&Bb[buf][row * 32 + slot * 8]);
    }
#pragma unroll
    for (int rt = 0; rt < 4; ++rt)
#pragma unroll
      for (int nt = 0; nt < 4; ++nt)
        acc[rt][nt] = __builtin_amdgcn_mfma_f32_16x16x32_bf16(af[rt], bfr[nt], acc[rt][nt], 0, 0, 0);
    __syncthreads();
  }

#pragma unroll
  for (int rt = 0; rt < 4; ++rt)
#pragma unroll
    for (int nt = 0; nt < 4; ++nt) {
      const int col = n0 + wc * 64 + nt * 16 + c;
#pragma unroll
      for (int r = 0; r < 4; ++r) {
        const int m = m0 + wr * 64 + rt * 16 + g * 4 + r;
        const float v = acc[rt][nt][r];
        if (MODE == 0) {
          const int sec = col >> 9, hh = (col >> 6) & 7, dh = col & 63;
          const int bh = (m >> 12) * 8 + hh, n = m & 4095;
          const size_t idx = (size_t)(bh * 4096 + n) * 64 + dh;
          if (sec == 0)      Qb[idx] = f2bf(v * 0.125f);  // fold 1/sqrt(d); exact pow2
          else if (sec == 1) Kb[idx] = f2bf(v);
          else               Vb[idx] = f2bf(v);
        } else {
          Cout[(size_t)m * 512 + col] = v + bias[col];
        }
      }
    }
}

// ------------------------------------------- V transpose: [bh][n][64] -> [bh][64][n]
__global__ __launch_bounds__(256) void vtrans_kernel(
    const unsigned short* __restrict__ Vb, unsigned short* __restrict__ Vtb) {
  __shared__ unsigned short tl[64][72];          // 72: 16B-aligned rows, bank-spread
  const int tid = threadIdx.x;
  const int bh = blockIdx.x >> 6, nt = blockIdx.x & 63;
  const int n0 = nt * 64;
  const unsigned short* src = Vb + ((size_t)bh * 4096 + n0) * 64;
#pragma unroll
  for (int h = 0; h < 2; ++h) {
    const int r = (tid >> 3) + h * 32;
    const int c0 = (tid & 7) * 8;
    *(short8v*)&tl[r][c0] = *(const short8v*)(src + r * 64 + c0);
  }
  __syncthreads();
#pragma unroll
  for (int h = 0; h < 2; ++h) {
    const int d = (tid >> 3) + h * 32;
    const int m0 = (tid & 7) * 8;
    unsigned short tmp[8];
#pragma unroll
    for (int i = 0; i < 8; ++i) tmp[i] = tl[m0 + i][d];
    *(short8v*)(Vtb + ((size_t)bh * 64 + d) * 4096 + n0 + m0) = *(const short8v*)&tmp[0];
  }
}

// ---------------------------------------------------------------- attention
// (unchanged from round 8 — PASSED at 88 us, MfmaUtil 36 / VALUBusy 53 / 0 conflicts)
// grid 1024 = chunk*512 + qb*16 + bh. Split-KV x2 (2048 keys per block).
// 4 waves x 32 q-rows, KV tile 64, no-max softmax P = __expf(S), S = q.k/8.
// Swapped QK^T -> in-register P via permlane swaps; rowsums via mfma(P, ones).
__global__ __launch_bounds__(256, 4) void attn_kernel(
    const unsigned short* __restrict__ Qb, const unsigned short* __restrict__ Kb,
    const unsigned short* __restrict__ Vtb, float* __restrict__ Opart,
    float* __restrict__ spart) {
  __shared__ short Kbuf[2][64 * 64];
  __shared__ short Vbuf[2][64 * 64];
  const int tid = threadIdx.x;
  const int w = tid >> 6, l = tid & 63;
  const int g = l >> 4, c = l & 15, c7 = l & 7;
  const int bh = blockIdx.x & 15;
  const int qb = (blockIdx.x >> 4) & 31;        // 0..31
  const int chunk = blockIdx.x >> 9;            // 0..1
  const int q0 = qb * 128 + w * 32;
  const unsigned short* Qp = Qb + (size_t)(bh * 4096 + q0) * 64;
  const unsigned short* Kp = Kb + (size_t)bh * 4096 * 64;
  const unsigned short* Vp = Vtb + (size_t)bh * 64 * 4096;

  // Q as B-fragments: lane holds Q[q = qt*16+c][d = kk*32 + g*8 + j] (pre-scaled)
  bf16x8 qf[2][2];
#pragma unroll
  for (int qt = 0; qt < 2; ++qt)
#pragma unroll
    for (int kk = 0; kk < 2; ++kk)
      qf[qt][kk] = __builtin_bit_cast(bf16x8,
          *(const short8v*)(Qp + (size_t)(qt * 16 + c) * 64 + kk * 32 + g * 8));

  // ones B-fragment for rowsum-by-MFMA
  short8v ones_s;
#pragma unroll
  for (int i = 0; i < 8; ++i) ones_s[i] = (short)0x3f80;  // bf16 1.0
  const bf16x8 ones = __builtin_bit_cast(bf16x8, ones_s);

  f32x4 O[2][4] = {};
  f32x4 osum[2] = {};

  auto STAGEKV = [&](int buf, int t) {         // t in [0,32)
    const int kv0 = (chunk * 32 + t) * 64;
#pragma unroll
    for (int j = 0; j < 2; ++j) {
      const int row = w * 16 + j * 8 + (l >> 3);
      const int gk = (l & 7) ^ (row & 7);        // pre-swizzled source
      gld16(&Kbuf[buf][(w * 16 + j * 8) * 64], Kp + (size_t)(kv0 + row) * 64 + gk * 8);
      gld16(&Vbuf[buf][(w * 16 + j * 8) * 64], Vp + (size_t)row * 4096 + kv0 + gk * 8);
    }
  };

  STAGEKV(0, 0);
  __syncthreads();

  for (int t = 0; t < 32; ++t) {
    const int buf = t & 1;
    if (t + 1 < 32) STAGEKV(buf ^ 1, t + 1);

    // ---- swapped QK^T: S^T[key][q] = K . Q^T, exp, pack to u32 bf16-pairs.
    // xu[qt][kt][0] = keys kt*16+g*4+{0,1}; [1] = +{2,3}   (for q = qt*16+c)
    unsigned xu[2][4][2];
#pragma unroll
    for (int kt = 0; kt < 4; ++kt) {
      const int krow = kt * 16 + c;
      bf16x8 kf0 = __builtin_bit_cast(bf16x8,
          *(const short8v*)&Kbuf[buf][krow * 64 + ((0 * 4 + g) ^ c7) * 8]);
      bf16x8 kf1 = __builtin_bit_cast(bf16x8,
          *(const short8v*)&Kbuf[buf][krow * 64 + ((1 * 4 + g) ^ c7) * 8]);
#pragma unroll
      for (int qt = 0; qt < 2; ++qt) {
        f32x4 S = {};
        S = __builtin_amdgcn_mfma_f32_16x16x32_bf16(kf0, qf[qt][0], S, 0, 0, 0);
        S = __builtin_amdgcn_mfma_f32_16x16x32_bf16(kf1, qf[qt][1], S, 0, 0, 0);
        const float p0 = __expf(S[0]);
        const float p1 = __expf(S[1]);
        const float p2 = __expf(S[2]);
        const float p3 = __expf(S[3]);
        xu[qt][kt][0] = pack2bf(p0, p1);       // compiler-visible TRANS consumer
        xu[qt][kt][1] = pack2bf(p2, p3);
      }
    }

    // ---- PV with in-register P: per (kk): A-frag(lane g,c) needs
    // P[q=c][keys kk*32+g*8..+7] = quads (kt=2kk..2kk+1, g_src=0..3).
    // swap32 then swap16 on the (kt_lo, kt_hi) u-pairs lands exactly that.
#pragma unroll
    for (int kk = 0; kk < 2; ++kk) {
      bf16x8 vf[4];
#pragma unroll
      for (int nt = 0; nt < 4; ++nt) {
        const int vrow = nt * 16 + c;
        vf[nt] = __builtin_bit_cast(bf16x8,
            *(const short8v*)&Vbuf[buf][vrow * 64 + (((kk * 4 + g) ^ c7) * 8)]);
      }
#pragma unroll
      for (int rt = 0; rt < 2; ++rt) {
        unsigned a0 = xu[rt][2 * kk][0], a2 = xu[rt][2 * kk + 1][0];
        asm("v_permlane32_swap_b32 %0, %1" : "+v"(a0), "+v"(a2));
        asm("v_permlane16_swap_b32 %0, %1" : "+v"(a0), "+v"(a2));
        unsigned a1 = xu[rt][2 * kk][1], a3 = xu[rt][2 * kk + 1][1];
        asm("v_permlane32_swap_b32 %0, %1" : "+v"(a1), "+v"(a3));
        asm("v_permlane16_swap_b32 %0, %1" : "+v"(a1), "+v"(a3));
        uint4v av; av[0] = a0; av[1] = a1; av[2] = a2; av[3] = a3;
        const bf16x8 pa = __builtin_bit_cast(bf16x8, av);
        __builtin_amdgcn_s_setprio(1);
        osum[rt] = __builtin_amdgcn_mfma_f32_16x16x32_bf16(pa, ones, osum[rt], 0, 0, 0);
#pragma unroll
        for (int nt = 0; nt < 4; ++nt)
          O[rt][nt] = __builtin_amdgcn_mfma_f32_16x16x32_bf16(pa, vf[nt], O[rt][nt], 0, 0, 0);
        __builtin_amdgcn_s_setprio(0);
      }
    }
    __syncthreads();
  }

  // ---- write partial O (unnormalized fp32) + rowsums
  float* Op = Opart + ((size_t)(chunk * 16 + bh) * 4096 + q0) * 64;
#pragma unroll
  for (int rt = 0; rt < 2; ++rt) {
#pragma unroll
    for (int nt = 0; nt < 4; ++nt)
#pragma unroll
      for (int r = 0; r < 4; ++r)
        Op[(size_t)(rt * 16 + g * 4 + r) * 64 + nt * 16 + c] = O[rt][nt][r];
    if (c == 0) {
#pragma unroll
      for (int r = 0; r < 4; ++r)
        spart[(size_t)(chunk * 16 + bh) * 4096 + q0 + rt * 16 + g * 4 + r] = osum[rt][r];
    }
  }
}

// ------------------------------------------- combine: (O0+O1)/(s0+s1) -> bf16
__global__ __launch_bounds__(256) void combine_kernel(
    const float* __restrict__ Opart, const float* __restrict__ spart,
    unsigned short* __restrict__ attnb) {
  const size_t CH = (size_t)16 * 4096 * 64;      // chunk stride (elems)
  const int gid = blockIdx.x * 256 + threadIdx.x;
  const size_t i = (size_t)gid * 4;              // into [16][4096][64]
  const int d = (int)(i & 63);
  const int bhq = (int)(i >> 6);                 // bh*4096 + q
  const f32x4 o0 = *(const f32x4*)(Opart + i);
  const f32x4 o1 = *(const f32x4*)(Opart + CH + i);
  const float inv = 1.0f / (spart[bhq] + spart[bhq + 16 * 4096]);
  const int bh = bhq >> 12, q = bhq & 4095;
  const int tok = (bh >> 3) * 4096 + q;
  const int col = (bh & 7) * 64 + d;
  unsigned u0, u1;
  const float r0 = (o0[0] + o1[0]) * inv, r1 = (o0[1] + o1[1]) * inv;
  const float r2 = (o0[2] + o1[2]) * inv, r3 = (o0[3] + o1[3]) * inv;
  u0 = (unsigned)f2bf(r0) | ((unsigned)f2bf(r1) << 16);
  u1 = (unsigned)f2bf(r2) | ((unsigned)f2bf(r3) << 16);
  *(uint2*)(attnb + (size_t)tok * 512 + col) = make_uint2(u0, u1);
}

// ---------------------------------------------------------------- launch
extern "C" void kernel_launch(void* const* d_in, const int* in_sizes, int n_in,
                              void* d_out, int out_size, void* d_ws, size_t ws_size,
                              hipStream_t stream) {
  (void)in_sizes; (void)n_in; (void)out_size; (void)ws_size;
  const float* x     = (const float*)d_in[0];
  const float* gamma = (const float*)d_in[1];
  const float* beta  = (const float*)d_in[2];
  const float* wqkv  = (const float*)d_in[3];
  const float* wout  = (const float*)d_in[4];
  const float* bout  = (const float*)d_in[5];
  float* out = (float*)d_out;

  char* ws = (char*)d_ws;
  size_t off = 0;
  auto alloc = [&](size_t bytes) {
    void* p = ws + off;
    off += (bytes + 255) & ~(size_t)255;
    return p;
  };
  unsigned*       xnb   = (unsigned*)alloc((size_t)MTOK * DIMF * 2);
  unsigned short* wqkvT = (unsigned short*)alloc((size_t)1536 * 512 * 2);
  unsigned short* woT   = (unsigned short*)alloc((size_t)512 * 512 * 2);
  unsigned short* Qbuf  = (unsigned short*)alloc((size_t)NBH * NSEQ * DHEAD * 2);
  unsigned short* Kb    = (unsigned short*)alloc((size_t)NBH * NSEQ * DHEAD * 2);
  unsigned short* Vtb   = (unsigned short*)alloc((size_t)NBH * NSEQ * DHEAD * 2);
  unsigned short* attnb = (unsigned short*)alloc((size_t)MTOK * DIMF * 2);
  float*          Opart = (float*)alloc((size_t)2 * NBH * NSEQ * DHEAD * 4);
  float*          spart = (float*)alloc((size_t)2 * NBH * NSEQ * 4);
  unsigned short* Vb    = attnb;   // alias: Vb consumed by vtrans before combine writes attnb

  ln_kernel<<<dim3(MTOK), dim3(256), 0, stream>>>(x, gamma, beta, xnb);
  wprep_kernel<<<dim3(256), dim3(256), 0, stream>>>(wqkv, wout, wqkvT, woT);
  gemm_kernel<0><<<dim3(64 * 12), dim3(256), 0, stream>>>(
      (const unsigned short*)xnb, wqkvT, Qbuf, Kb, Vb, nullptr, nullptr, 1536);
  vtrans_kernel<<<dim3(NBH * 64), dim3(256), 0, stream>>>(Vb, Vtb);
  attn_kernel<<<dim3(1024), dim3(256), 0, stream>>>(Qbuf, Kb, Vtb, Opart, spart);
  combine_kernel<<<dim3(4096), dim3(256), 0, stream>>>(Opart, spart, attnb);
  gemm_kernel<1><<<dim3(64 * 4), dim3(256), 0, stream>>>(
      attnb, woT, nullptr, nullptr, nullptr, bout, out, 512);
}